// Round 7
// baseline (318.566 us; speedup 1.0000x reference)
//
#include <hip/hip_runtime.h>
#include <stdint.h>

// Pipeline: cvt(fp32->bf16) -> gemm_m2<0> QKV (256x256xBK64, m201-style 8-phase schedule,
//           scatter Q/K [BH][S][D], V^T [BH][D][S]) -> rope -> flash attention -> gemm_m2<1>.
//
// gemm_m2: BM=BN=256, BK=64, 2 LDS buffers (128KB), 8 waves (2Mx4N), wave tile 128x64.
// Iteration = 2 K-steps (tau=2i from buf0 phases 1-4, tau+1 from buf1 phases 5-8).
// Phase p: [12 or 0 ds_read_b128] [2-gld stage] BARRIER lgkmcnt(0) setprio(1) 16 MFMA
//          setprio(0) [vmcnt(4) @ph4/ph8] BARRIER.
// Reads front-loaded: ph1 reads all k0 frags, ph2 all k1 -> buf's reads complete at ph2's
// post-MFMA barrier. Stage slots (iter i): ph1: B-lo(2i+1) ph2: B-hi(2i+1) ph3: A-lo(2i+2)
// ph4: A-hi(2i+2) ph5: B-lo(2i+2) ph6: B-hi(2i+2) ph7: A-lo(2i+3) ph8: A-hi(2i+3).
// Race proof: (a) overwrite-safety: each stage targets a buffer component whose last ds_read
// completed >=1 post-MFMA barrier earlier (e.g. ph3's A(2i+2)->As[0]: As[0] reads done at
// ph2's lgkm+barrier). (b) landing: gate vmcnt(4)@ph4 leaves ph3,4's 4 loads in flight ->
// drains B(2i+1) [read ph5] and everything older; gate@ph8 leaves ph7,8 -> drains A/B(2i+2)
// [read next ph1]. Prologue stages step0 full + step1 A (12 loads), vmcnt(4) -> step0 landed.
// Tail: stage() no-ops for step>=nk; last iter ph4 uses vmcnt(0) (B(31) staged ph1,2 same iter).

#define SCALE_Q 0.08838834764831845f

typedef short bf16x8 __attribute__((ext_vector_type(8)));
typedef float f32x4 __attribute__((ext_vector_type(4)));
typedef unsigned short u16x4v __attribute__((ext_vector_type(4)));
typedef unsigned short u16x8v __attribute__((ext_vector_type(8)));

__device__ __forceinline__ unsigned short f2bf(float f) {
  unsigned u = __float_as_uint(f);
  return (unsigned short)((u + 0x7FFFu + ((u >> 16) & 1u)) >> 16);  // RNE
}
__device__ __forceinline__ float bf2f(unsigned short h) {
  return __uint_as_float(((unsigned)h) << 16);
}
__device__ __forceinline__ void gld16(void* lds, const void* g) {
  __builtin_amdgcn_global_load_lds(
      (const __attribute__((address_space(1))) unsigned int*)g,
      (__attribute__((address_space(3))) unsigned int*)lds, 16, 0, 0);
}

#define BAR __builtin_amdgcn_s_barrier()
#define SB0 __builtin_amdgcn_sched_barrier(0)
#define LGKM0 asm volatile("s_waitcnt lgkmcnt(0)" ::: "memory")
#define VM4 asm volatile("s_waitcnt vmcnt(4)" ::: "memory")
#define VM0 asm volatile("s_waitcnt vmcnt(0)" ::: "memory")
#define PRIO1 __builtin_amdgcn_s_setprio(1)
#define PRIO0 __builtin_amdgcn_s_setprio(0)

// ---------------- fp32 -> bf16 conversion (5 regions via blockIdx.y) ----------------
__global__ __launch_bounds__(256) void cvt_all(
    const float* __restrict__ x, const float* __restrict__ wq,
    const float* __restrict__ wk, const float* __restrict__ wv,
    const float* __restrict__ wo,
    unsigned short* __restrict__ xb, unsigned short* __restrict__ wqkv,
    unsigned short* __restrict__ wob) {
  int r = blockIdx.y;
  size_t i = ((size_t)blockIdx.x * 256 + threadIdx.x) * 8;
  const float* src; unsigned short* dst; size_t n;
  if (r == 0)      { src = x;  dst = xb;             n = 8388608; }
  else if (r == 1) { src = wq; dst = wqkv;           n = 4194304; }
  else if (r == 2) { src = wk; dst = wqkv + 4194304; n = 4194304; }
  else if (r == 3) { src = wv; dst = wqkv + 8388608; n = 4194304; }
  else             { src = wo; dst = wob;            n = 4194304; }
  if (i >= n) return;
  float4 a = *(const float4*)(src + i);
  float4 b = *(const float4*)(src + i + 4);
  u16x8v o;
  o[0] = f2bf(a.x); o[1] = f2bf(a.y); o[2] = f2bf(a.z); o[3] = f2bf(a.w);
  o[4] = f2bf(b.x); o[5] = f2bf(b.y); o[6] = f2bf(b.z); o[7] = f2bf(b.w);
  *(u16x8v*)(dst + i) = o;
}

// ---------------- RoPE tables ----------------
__global__ __launch_bounds__(256) void rope_table(float* __restrict__ ct, float* __restrict__ st) {
  int id = blockIdx.x * 256 + threadIdx.x;  // 131072 = 2048*64
  int s = id >> 6, j = id & 63;
  float inv = __powf(10000.0f, -(float)j * (1.0f / 64.0f));
  float a = (float)s * inv;
  ct[id] = __cosf(a);
  st[id] = __sinf(a);
}

// ---------------- 256x256xBK64 8-phase GEMM: C = A[M][K] @ B[N][K]^T ----------------
// LDS per buffer: A [256 rows][64 k] bf16 (128B rows, 8x16B slots, swz slot^(row&7)) + B same.
// Staged linearly via gld16 with pre-swizzled global source. Grid: 16 rows x nbx cols (nbx%8==0).
// MODE 0: scatter Q/K [BH][S][128], V^T [BH][128][S].  MODE 1: fp32 C0[row*N+col].
template <int MODE>
__global__ __launch_bounds__(512, 2) void gemm_m2(
    const unsigned short* __restrict__ A, const unsigned short* __restrict__ B,
    void* __restrict__ C0, void* __restrict__ C1, void* __restrict__ C2,
    int N, int Kd, int nbx) {
  __shared__ unsigned short As[2][256 * 64];   // 2 x 32KB
  __shared__ unsigned short Bs[2][256 * 64];   // 2 x 32KB
  const int t = threadIdx.x;
  const int lane = t & 63, w = t >> 6;
  const int g = lane >> 4, c15 = lane & 15;
  const int wm = w >> 2, wn = w & 3;

  // 2-D XCD chunking: chunk = bid&7 owns all 16 row-tiles x (nbx/8) col-tiles, col-major.
  const int chunk = (int)blockIdx.x & 7;
  const int idx = (int)blockIdx.x >> 3;
  const int cpc = nbx >> 3;
  const int row = idx & 15;
  const int col = chunk * cpc + (idx >> 4);
  const int brow = row * 256, bcol = col * 256;

  // staging source (pre-swizzled): thread t covers ldsrow r8 = t>>3 (+64/128/192), phys slot t&7.
  const int r8 = t >> 3;
  const int lg = (t & 7) ^ (r8 & 7);
  const unsigned short* srcA = A + (size_t)(brow + r8) * Kd + lg * 8;
  const unsigned short* srcB = B + (size_t)(bcol + r8) * Kd + lg * 8;

  const int nk = Kd >> 6;   // K-steps of 64 (32 here)
  const int nit = nk >> 1;  // iterations (16)

  // stage one component: comp 0=A-lo(rows 0-127) 1=A-hi 2=B-lo 3=B-hi; 2 gld16/thread = 16KB
  auto stage = [&](int step, int comp) {
    if (step >= nk) return;
    char* dst = ((comp & 2) ? (char*)Bs[step & 1] : (char*)As[step & 1]) + (comp & 1) * 16384;
    const unsigned short* src =
        ((comp & 2) ? srcB : srcA) + (size_t)((comp & 1) * 128) * Kd + step * 64;
    gld16(dst + t * 16, src);
    gld16(dst + 8192 + t * 16, src + (size_t)64 * Kd);
  };

  // fragment addressing: A row = wm*128 + mi*16 + c15; B row = wn*64 + nj*16 + c15;
  // slot = (k2*4+g) ^ (row&7), row&7 == c15&7. 2-way max bank aliasing (free).
  const int aBase = (wm * 128 + c15) * 128;
  const int bBase = (wn * 64 + c15) * 128;
  const int sl0 = ((g) ^ (c15 & 7)) * 16;
  const int sl1 = ((4 + g) ^ (c15 & 7)) * 16;

  f32x4 zero4 = {0.f, 0.f, 0.f, 0.f};
  f32x4 acc[8][4];
#pragma unroll
  for (int a_ = 0; a_ < 8; ++a_)
#pragma unroll
    for (int b_ = 0; b_ < 4; ++b_) acc[a_][b_] = zero4;

  bf16x8 af0[8], bf0[4], af1[8], bf1[4];

  auto RD = [&](const char* ab, const char* bb, bf16x8* AF, bf16x8* BF, int sl) {
#pragma unroll
    for (int mi = 0; mi < 8; ++mi) AF[mi] = *(const bf16x8*)(ab + aBase + mi * 2048 + sl);
#pragma unroll
    for (int nj = 0; nj < 4; ++nj) BF[nj] = *(const bf16x8*)(bb + bBase + nj * 2048 + sl);
  };
  auto MF16 = [&](const bf16x8* AF, const bf16x8* BF, int mb) {
#pragma unroll
    for (int mi = 0; mi < 4; ++mi)
#pragma unroll
      for (int nj = 0; nj < 4; ++nj)
        acc[mb + mi][nj] = __builtin_amdgcn_mfma_f32_16x16x32_bf16(
            AF[mb + mi], BF[nj], acc[mb + mi][nj], 0, 0, 0);
  };

  // prologue: step0 full (A-lo,A-hi,B-lo,B-hi) + step1 A (A-lo,A-hi) = 12 loads
  stage(0, 0); stage(0, 1); stage(0, 2); stage(0, 3);
  stage(1, 0); stage(1, 1);
  VM4;                       // drain step0's 8; step1 A (4) in flight
  BAR; SB0;

  for (int i = 0; i < nit; ++i) {
    const char* a0 = (const char*)As[0]; const char* b0 = (const char*)Bs[0];
    const char* a1 = (const char*)As[1]; const char* b1 = (const char*)Bs[1];
    const int sB = 2 * i + 1, sN = 2 * i + 2, sN1 = 2 * i + 3;
    // ---- ph1: read k0 frags of step 2i (buf0); MFMA k0 x mi0-3
    RD(a0, b0, af0, bf0, sl0); stage(sB, 2);
    BAR; LGKM0; SB0;
    PRIO1; MF16(af0, bf0, 0); PRIO0;
    BAR; SB0;
    // ---- ph2: read k1 frags; MFMA k0 x mi4-7   (buf0 reads complete here)
    RD(a0, b0, af1, bf1, sl1); stage(sB, 3);
    BAR; LGKM0; SB0;
    PRIO1; MF16(af0, bf0, 4); PRIO0;
    BAR; SB0;
    // ---- ph3: MFMA k1 x mi0-3
    stage(sN, 0);
    BAR; SB0;
    PRIO1; MF16(af1, bf1, 0); PRIO0;
    BAR; SB0;
    // ---- ph4: MFMA k1 x mi4-7; gate
    stage(sN, 1);
    BAR; SB0;
    PRIO1; MF16(af1, bf1, 4); PRIO0;
    if (i + 1 == nit) { VM0; } else { VM4; }
    BAR; SB0;
    // ---- ph5: step 2i+1 (buf1), k0; MFMA k0 x mi0-3
    RD(a1, b1, af0, bf0, sl0); stage(sN, 2);
    BAR; LGKM0; SB0;
    PRIO1; MF16(af0, bf0, 0); PRIO0;
    BAR; SB0;
    // ---- ph6: read k1; MFMA k0 x mi4-7   (buf1 reads complete here)
    RD(a1, b1, af1, bf1, sl1); stage(sN, 3);
    BAR; LGKM0; SB0;
    PRIO1; MF16(af0, bf0, 4); PRIO0;
    BAR; SB0;
    // ---- ph7
    stage(sN1, 0);
    BAR; SB0;
    PRIO1; MF16(af1, bf1, 0); PRIO0;
    BAR; SB0;
    // ---- ph8: gate
    stage(sN1, 1);
    BAR; SB0;
    PRIO1; MF16(af1, bf1, 4); PRIO0;
    VM4;
    BAR; SB0;
  }

  // Epilogue. C/D layout: col = lane&15, row = (lane>>4)*4 + i  [m89]
#pragma unroll
  for (int mi = 0; mi < 8; ++mi) {
#pragma unroll
    for (int nj = 0; nj < 4; ++nj) {
      f32x4 v = acc[mi][nj];
      int row0 = brow + wm * 128 + mi * 16 + g * 4;
      int colc = bcol + wn * 64 + nj * 16 + c15;
      if (MODE == 0) {
        int which = colc >> 11;           // 0=Q 1=K 2=V
        int hc = colc & 2047;
        int bh = ((row0 >> 11) << 4) + (hc >> 7);
        int d = hc & 127, s0 = row0 & 2047;
        if (which == 2) {                 // V^T: [bh][d][s], i-values are s-contiguous
          u16x4v pk;
          pk[0] = f2bf(v[0]); pk[1] = f2bf(v[1]); pk[2] = f2bf(v[2]); pk[3] = f2bf(v[3]);
          *(u16x4v*)((unsigned short*)C2 + ((size_t)bh * 128 + d) * 2048 + s0) = pk;
        } else {
          unsigned short* dst =
              (unsigned short*)(which ? C1 : C0) + ((size_t)bh * 2048 + s0) * 128 + d;
#pragma unroll
          for (int i2 = 0; i2 < 4; ++i2) dst[(size_t)i2 * 128] = f2bf(v[i2]);
        }
      } else {
        float* Cf = (float*)C0;
#pragma unroll
        for (int i2 = 0; i2 < 4; ++i2) Cf[(size_t)(row0 + i2) * N + colc] = v[i2];
      }
    }
  }
}

// ---------------- RoPE (in-place on bf16 Q,K [BH][S][128]); Q gets 1/sqrt(128) folded ----------------
__global__ __launch_bounds__(256) void rope_apply(
    unsigned short* __restrict__ Q, unsigned short* __restrict__ K,
    const float* __restrict__ ct, const float* __restrict__ st) {
  int id = blockIdx.x * 256 + threadIdx.x;  // 524288 = 32*2048*8
  int o = id & 7;
  int s = (id >> 3) & 2047;
  int bh = id >> 14;
  size_t base = ((size_t)bh * 2048 + s) * 128 + o * 8;
  u16x8v qlo = *(u16x8v*)(Q + base), qhi = *(u16x8v*)(Q + base + 64);
  u16x8v klo = *(u16x8v*)(K + base), khi = *(u16x8v*)(K + base + 64);
  const float* cp = ct + s * 64 + o * 8;
  const float* sp = st + s * 64 + o * 8;
#pragma unroll
  for (int j = 0; j < 8; ++j) {
    float c = cp[j], sn = sp[j];
    float ql = bf2f(qlo[j]), qh = bf2f(qhi[j]);
    qlo[j] = f2bf((ql * c - qh * sn) * SCALE_Q);
    qhi[j] = f2bf((qh * c + ql * sn) * SCALE_Q);
    float kl = bf2f(klo[j]), kh = bf2f(khi[j]);
    klo[j] = f2bf(kl * c - kh * sn);
    khi[j] = f2bf(kh * c + kl * sn);
  }
  *(u16x8v*)(Q + base) = qlo; *(u16x8v*)(Q + base + 64) = qhi;
  *(u16x8v*)(K + base) = klo; *(u16x8v*)(K + base + 64) = khi;
}

// ---------------- causal flash attention: paired q-blocks + dbuf K/V (unchanged) ----------------
__global__ __launch_bounds__(256) void attn_fwd(
    const unsigned short* __restrict__ Qg, const unsigned short* __restrict__ Kg,
    const unsigned short* __restrict__ Vtg, unsigned short* __restrict__ Og) {
  __shared__ unsigned short Ks[2][64 * 128];
  __shared__ unsigned short Vs[2][64 * 128];
  __shared__ unsigned short Pl[4][16 * 88];
  const int t = threadIdx.x;
  const int lane = t & 63, w = t >> 6;
  const int g = lane >> 4, c15 = lane & 15;
  const int pair = blockIdx.x;
  const int bh = blockIdx.y;
  const int b = bh >> 4, h = bh & 15;

  const int ksrow = t >> 4;
  const int kssl = (t & 15) ^ ksrow;
  const unsigned short* kp = Kg + ((size_t)bh * 2048 + ksrow) * 128 + kssl * 8;
  const int vsrow = t >> 3;
  const int vssl = (t & 7) ^ (vsrow & 7);
  const unsigned short* vp = Vtg + ((size_t)bh * 128 + vsrow) * 2048 + vssl * 8;

  auto stageTile = [&](int buf, int tkv) {
#pragma unroll
    for (int c = 0; c < 4; ++c) {
      gld16((char*)Ks[buf] + c * 4096 + t * 16, kp + (size_t)(tkv * 64 + c * 16) * 128);
      gld16((char*)Vs[buf] + c * 4096 + t * 16, vp + (size_t)c * 32 * 2048 + tkv * 64);
    }
  };

  f32x4 zero4 = {0.f, 0.f, 0.f, 0.f};
  f32x4 o[8];
  float mrow[4], lrow[4];
  bf16x8 qf[4];

  auto computeTile = [&](int buf, int qb, int tkv) {
    const int q0 = qb * 64;
    const int qrow = q0 + w * 16;
    f32x4 sv[4];
    PRIO1;
#pragma unroll
    for (int cb = 0; cb < 4; ++cb) {
      f32x4 z = zero4;
#pragma unroll
      for (int kf = 0; kf < 4; ++kf) {
        int rowk = cb * 16 + c15;
        int p = (kf * 4 + g) ^ c15;
        bf16x8 kfr = *(const bf16x8*)((const char*)Ks[buf] + rowk * 256 + p * 16);
        z = __builtin_amdgcn_mfma_f32_16x16x32_bf16(qf[kf], kfr, z, 0, 0, 0);
      }
      sv[cb] = z;
    }
    PRIO0;
    if (tkv == qb) {
#pragma unroll
      for (int cb = 0; cb < 4; ++cb)
#pragma unroll
        for (int i = 0; i < 4; ++i) {
          int colk = q0 + cb * 16 + c15;
          int rq = qrow + g * 4 + i;
          if (colk > rq) sv[cb][i] = -1e30f;
        }
    }
    float pmx[4];
#pragma unroll
    for (int i = 0; i < 4; ++i)
      pmx[i] = fmaxf(fmaxf(sv[0][i], sv[1][i]), fmaxf(sv[2][i], sv[3][i]));
#pragma unroll
    for (int dd = 1; dd < 16; dd <<= 1)
#pragma unroll
      for (int i = 0; i < 4; ++i) pmx[i] = fmaxf(pmx[i], __shfl_xor(pmx[i], dd));
    float sc[4], psum[4];
#pragma unroll
    for (int i = 0; i < 4; ++i) {
      float nm = fmaxf(mrow[i], pmx[i]);
      sc[i] = __expf(mrow[i] - nm);
      mrow[i] = nm;
      psum[i] = 0.f;
    }
#pragma unroll
    for (int cb = 0; cb < 4; ++cb)
#pragma unroll
      for (int i = 0; i < 4; ++i) {
        float e = __expf(sv[cb][i] - mrow[i]);
        sv[cb][i] = e;
        psum[i] += e;
      }
#pragma unroll
    for (int dd = 1; dd < 16; dd <<= 1)
#pragma unroll
      for (int i = 0; i < 4; ++i) psum[i] += __shfl_xor(psum[i], dd);
#pragma unroll
    for (int i = 0; i < 4; ++i) lrow[i] = lrow[i] * sc[i] + psum[i];
#pragma unroll
    for (int db = 0; db < 8; ++db)
#pragma unroll
      for (int i = 0; i < 4; ++i) o[db][i] *= sc[i];

    unsigned short* pw = &Pl[w][0];
#pragma unroll
    for (int cb = 0; cb < 4; ++cb)
#pragma unroll
      for (int i = 0; i < 4; ++i)
        pw[(g * 4 + i) * 88 + cb * 16 + c15] = f2bf(sv[cb][i]);
    bf16x8 pf[2];
#pragma unroll
    for (int kb = 0; kb < 2; ++kb)
      pf[kb] = *(const bf16x8*)((const char*)pw + c15 * 176 + kb * 64 + g * 16);

    PRIO1;
#pragma unroll
    for (int db = 0; db < 8; ++db) {
#pragma unroll
      for (int kb = 0; kb < 2; ++kb) {
        int rowv = db * 16 + c15;
        int p = (kb * 4 + g) ^ (c15 & 7);
        bf16x8 vfr = *(const bf16x8*)((const char*)Vs[buf] + rowv * 128 + p * 16);
        o[db] = __builtin_amdgcn_mfma_f32_16x16x32_bf16(pf[kb], vfr, o[db], 0, 0, 0);
      }
    }
    PRIO0;
  };

  auto loadQ = [&](int qb) {
    const unsigned short* qp = Qg + ((size_t)bh * 2048 + qb * 64 + w * 16 + c15) * 128 + g * 8;
#pragma unroll
    for (int kf = 0; kf < 4; ++kf) qf[kf] = *(const bf16x8*)(qp + kf * 32);
#pragma unroll
    for (int db = 0; db < 8; ++db) o[db] = zero4;
#pragma unroll
    for (int i = 0; i < 4; ++i) { mrow[i] = -1e30f; lrow[i] = 0.f; }
  };

  auto writeO = [&](int qb) {
    float linv[4];
#pragma unroll
    for (int i = 0; i < 4; ++i) linv[i] = 1.0f / lrow[i];
#pragma unroll
    for (int db = 0; db < 8; ++db)
#pragma unroll
      for (int i = 0; i < 4; ++i) {
        int q = qb * 64 + w * 16 + g * 4 + i;
        Og[((size_t)(b * 2048 + q)) * 2048 + h * 128 + db * 16 + c15] =
            f2bf(o[db][i] * linv[i]);
      }
  };

  const int qbA = pair, qbB = 31 - pair;
  const int ntA = qbA + 1, ntB = qbB + 1;
  int cur = 0;

  stageTile(0, 0);
  loadQ(qbA);
  for (int tkv = 0; tkv < ntA; ++tkv) {
    __syncthreads();
    if (tkv + 1 < ntA) stageTile(cur ^ 1, tkv + 1);
    else               stageTile(cur ^ 1, 0);
    computeTile(cur, qbA, tkv);
    cur ^= 1;
  }
  writeO(qbA);
  loadQ(qbB);
  for (int tkv = 0; tkv < ntB; ++tkv) {
    __syncthreads();
    if (tkv + 1 < ntB) stageTile(cur ^ 1, tkv + 1);
    computeTile(cur, qbB, tkv);
    cur ^= 1;
  }
  writeO(qbB);
}

extern "C" void kernel_launch(void* const* d_in, const int* in_sizes, int n_in,
                              void* d_out, int out_size, void* d_ws, size_t ws_size,
                              hipStream_t stream) {
  const float* x  = (const float*)d_in[0];
  const float* Wq = (const float*)d_in[1];
  const float* Wk = (const float*)d_in[2];
  const float* Wv = (const float*)d_in[3];
  const float* Wo = (const float*)d_in[4];
  char* p = (char*)d_ws;
  unsigned short* xb    = (unsigned short*)p;                 // 16 MB (reused as Ao)
  unsigned short* wqkvb = (unsigned short*)(p + 16777216);    // 24 MB
  unsigned short* wob   = (unsigned short*)(p + 41943040);    //  8 MB
  unsigned short* Qb    = (unsigned short*)(p + 50331648);    // 16 MB
  unsigned short* Kb    = (unsigned short*)(p + 67108864);    // 16 MB
  unsigned short* Vt    = (unsigned short*)(p + 83886080);    // 16 MB
  float* ctab           = (float*)(p + 100663296);            // 0.5 MB
  float* stab           = (float*)(p + 101187584);            // 0.5 MB -> end 101711872
  unsigned short* Ao = xb;  // xb dead after gemm_qkv

  cvt_all<<<dim3(4096, 5), 256, 0, stream>>>(x, Wq, Wk, Wv, Wo, xb, wqkvb, wob);
  rope_table<<<512, 256, 0, stream>>>(ctab, stab);
  gemm_m2<0><<<384, 512, 0, stream>>>(xb, wqkvb, Qb, Kb, Vt, 6144, 2048, 24);
  rope_apply<<<2048, 256, 0, stream>>>(Qb, Kb, ctab, stab);
  attn_fwd<<<dim3(16, 32), 256, 0, stream>>>(Qb, Kb, Vt, Ao);
  gemm_m2<1><<<128, 512, 0, stream>>>(Ao, wob, d_out, nullptr, nullptr, 2048, 2048, 8);
}

// Round 9
// 297.095 us; speedup vs baseline: 1.0723x; 1.0723x over previous
//
#include <hip/hip_runtime.h>
#include <stdint.h>

// Pipeline: cvt(fp32->bf16) -> gemm8p2 QKV (256x256x32, 2-deep ring, 64KB LDS,
//           2 blocks/CU co-resident, single-round 384-block grid; scatter Q/K [BH][S][D],
//           V^T [BH][D][S]) -> rope tables -> rope -> causal flash attention (paired
//           q-blocks, dbuf) -> gemm_bt out-proj (128^2, 3-4 blocks/CU, R2-proven).
//
// gemm8p2 K-tile: 12 ds_read_b128 (bfv4, af0 4 | pin | af1 4); stage(kt+1) 4x gld16;
// lgkm(4) -> 16 MFMA; lgkm(0) -> 16 MFMA; vmcnt(0); barrier.  The vmcnt(0) drain is the
// m97 pattern; 2 blocks/CU cover it (m114 overlap).  Race: stage(kt+1) overwrites
// buf[kt-1] whose reads drained before barrier(kt-1); buf[kt+1] published by drain+barrier.

#define SCALE_Q 0.08838834764831845f

typedef short bf16x8 __attribute__((ext_vector_type(8)));
typedef float f32x4 __attribute__((ext_vector_type(4)));
typedef unsigned short u16x4v __attribute__((ext_vector_type(4)));
typedef unsigned short u16x8v __attribute__((ext_vector_type(8)));

__device__ __forceinline__ unsigned short f2bf(float f) {
  unsigned u = __float_as_uint(f);
  return (unsigned short)((u + 0x7FFFu + ((u >> 16) & 1u)) >> 16);  // RNE
}
__device__ __forceinline__ float bf2f(unsigned short h) {
  return __uint_as_float(((unsigned)h) << 16);
}
__device__ __forceinline__ void gld16(void* lds, const void* g) {
  __builtin_amdgcn_global_load_lds(
      (const __attribute__((address_space(1))) unsigned int*)g,
      (__attribute__((address_space(3))) unsigned int*)lds, 16, 0, 0);
}

// ---------------- fp32 -> bf16 conversion (5 regions via blockIdx.y) ----------------
__global__ __launch_bounds__(256) void cvt_all(
    const float* __restrict__ x, const float* __restrict__ wq,
    const float* __restrict__ wk, const float* __restrict__ wv,
    const float* __restrict__ wo,
    unsigned short* __restrict__ xb, unsigned short* __restrict__ wqkv,
    unsigned short* __restrict__ wob) {
  int r = blockIdx.y;
  size_t i = ((size_t)blockIdx.x * 256 + threadIdx.x) * 8;
  const float* src; unsigned short* dst; size_t n;
  if (r == 0)      { src = x;  dst = xb;             n = 8388608; }
  else if (r == 1) { src = wq; dst = wqkv;           n = 4194304; }
  else if (r == 2) { src = wk; dst = wqkv + 4194304; n = 4194304; }
  else if (r == 3) { src = wv; dst = wqkv + 8388608; n = 4194304; }
  else             { src = wo; dst = wob;            n = 4194304; }
  if (i >= n) return;
  float4 a = *(const float4*)(src + i);
  float4 b = *(const float4*)(src + i + 4);
  u16x8v o;
  o[0] = f2bf(a.x); o[1] = f2bf(a.y); o[2] = f2bf(a.z); o[3] = f2bf(a.w);
  o[4] = f2bf(b.x); o[5] = f2bf(b.y); o[6] = f2bf(b.z); o[7] = f2bf(b.w);
  *(u16x8v*)(dst + i) = o;
}

// ---------------- RoPE tables ----------------
__global__ __launch_bounds__(256) void rope_table(float* __restrict__ ct, float* __restrict__ st) {
  int id = blockIdx.x * 256 + threadIdx.x;  // 131072 = 2048*64
  int s = id >> 6, j = id & 63;
  float inv = __powf(10000.0f, -(float)j * (1.0f / 64.0f));
  float a = (float)s * inv;
  ct[id] = __cosf(a);
  st[id] = __sinf(a);
}

// ---------------- 256x256x32 GEMM, 2-deep ring, 2 blocks/CU: C = A[M][K] @ B[N][K]^T ----
// 512 threads, 8 waves (wm 0..1, wn 0..3), wave tile 128x64.
// LDS per buffer: A 16KB packed [128 ldsrows][128B] (ldsrow L = A-rows L and L+128;
// 16B slots 0-3 = row L k-chunks, 4-7 = row L+128), swz phys = slot ^ (L&7). B same.
// Grid: 16 row-tiles x nbx col-tiles (nbx%8==0); 2-D XCD chunking col-major.
// Scatters Q/K [BH][S][128], V^T [BH][128][S].
__global__ __launch_bounds__(512, 2) void gemm8p2(
    const unsigned short* __restrict__ A, const unsigned short* __restrict__ B,
    void* __restrict__ C0, void* __restrict__ C1, void* __restrict__ C2,
    int N, int Kd, int nbx) {
  __shared__ unsigned short As[2][128 * 64];   // 2 x 16KB
  __shared__ unsigned short Bs[2][128 * 64];   // 2 x 16KB
  const int t = threadIdx.x;
  const int lane = t & 63, w = t >> 6;
  const int g = lane >> 4, c15 = lane & 15;
  const int wm = w >> 2, wn = w & 3;

  // 2-D XCD chunking: chunk = bid&7 owns all 16 row-tiles x (nbx/8) col-tiles, col-major.
  const int chunk = (int)blockIdx.x & 7;
  const int idx = (int)blockIdx.x >> 3;
  const int cpc = nbx >> 3;
  const int row = idx & 15;
  const int col = chunk * cpc + (idx >> 4);
  const int brow = row * 256, bcol = col * 256;

  // staging source (pre-swizzled): thread t covers ldsrow l = t>>3, phys slot t&7.
  const int l = t >> 3;
  const int lg = (t & 7) ^ (l & 7);            // logical slot at this phys slot
  const unsigned short* srcA = A + (size_t)(brow + l + ((lg >> 2) << 7)) * Kd + (lg & 3) * 8;
  const unsigned short* srcB = B + (size_t)(bcol + l + ((lg >> 2) << 7)) * Kd + (lg & 3) * 8;

  auto stage = [&](int kt) {
    const int buf = kt & 1;
    const unsigned short* a = srcA + kt * 32;
    const unsigned short* b = srcB + kt * 32;
    gld16((char*)As[buf] + t * 16, a);                           // ldsrows 0..63
    gld16((char*)As[buf] + 8192 + t * 16, a + (size_t)64 * Kd);  // ldsrows 64..127
    gld16((char*)Bs[buf] + t * 16, b);
    gld16((char*)Bs[buf] + 8192 + t * 16, b + (size_t)64 * Kd);
  };

  // fragment base offsets; frag i at base + i*2048 (16 rows * 128B)
  const int aoff = c15 * 128 + ((((wm << 2) | g) ^ (c15 & 7)) << 4);
  const int boff = ((wn & 1) << 13) + c15 * 128 + (((((wn >> 1) << 2) | g) ^ (c15 & 7)) << 4);

  f32x4 zero4 = {0.f, 0.f, 0.f, 0.f};
  f32x4 acc[8][4];
#pragma unroll
  for (int a_ = 0; a_ < 8; ++a_)
#pragma unroll
    for (int b_ = 0; b_ < 4; ++b_) acc[a_][b_] = zero4;

  const int nk = Kd >> 5;  // 64
  stage(0);
  asm volatile("s_waitcnt vmcnt(0)" ::: "memory");
  __builtin_amdgcn_s_barrier();

  for (int kt = 0; kt < nk; ++kt) {
    const char* ab = (const char*)As[kt & 1];
    const char* bb = (const char*)Bs[kt & 1];
    bf16x8 bfv[4], af0[4], af1[4];
#pragma unroll
    for (int nj = 0; nj < 4; ++nj) bfv[nj] = *(const bf16x8*)(bb + boff + nj * 2048);
#pragma unroll
    for (int mi = 0; mi < 4; ++mi) af0[mi] = *(const bf16x8*)(ab + aoff + mi * 2048);
    __builtin_amdgcn_sched_barrier(0);          // pin issue order: bfv+af0 before af1
#pragma unroll
    for (int mi = 0; mi < 4; ++mi) af1[mi] = *(const bf16x8*)(ab + aoff + (mi + 4) * 2048);
    if (kt + 1 < nk) stage(kt + 1);             // overwrites buf[kt-1] — safe per barrier@kt-1
    asm volatile("s_waitcnt lgkmcnt(4)" ::: "memory");  // bfv+af0 done; af1 in flight
    __builtin_amdgcn_sched_barrier(0);
    __builtin_amdgcn_s_setprio(1);
#pragma unroll
    for (int mi = 0; mi < 4; ++mi)
#pragma unroll
      for (int nj = 0; nj < 4; ++nj)
        acc[mi][nj] = __builtin_amdgcn_mfma_f32_16x16x32_bf16(
            af0[mi], bfv[nj], acc[mi][nj], 0, 0, 0);
    __builtin_amdgcn_s_setprio(0);
    asm volatile("s_waitcnt lgkmcnt(0)" ::: "memory");  // af1 done (drained under cluster 0)
    __builtin_amdgcn_sched_barrier(0);
    __builtin_amdgcn_s_setprio(1);
#pragma unroll
    for (int mi = 0; mi < 4; ++mi)
#pragma unroll
      for (int nj = 0; nj < 4; ++nj)
        acc[mi + 4][nj] = __builtin_amdgcn_mfma_f32_16x16x32_bf16(
            af1[mi], bfv[nj], acc[mi + 4][nj], 0, 0, 0);
    __builtin_amdgcn_s_setprio(0);
    asm volatile("s_waitcnt vmcnt(0)" ::: "memory");    // buf[kt+1] landed (m97 drain;
    __builtin_amdgcn_s_barrier();                       //  covered by co-resident block)
  }

  // Epilogue (QKV scatter). C/D layout: col = lane&15, row = (lane>>4)*4 + i  [m89]
#pragma unroll
  for (int mi = 0; mi < 8; ++mi) {
#pragma unroll
    for (int nj = 0; nj < 4; ++nj) {
      f32x4 v = acc[mi][nj];
      int row0 = brow + wm * 128 + mi * 16 + g * 4;
      int colc = bcol + wn * 64 + nj * 16 + c15;
      int which = colc >> 11;           // 0=Q 1=K 2=V
      int hc = colc & 2047;
      int bh = ((row0 >> 11) << 4) + (hc >> 7);
      int d = hc & 127, s0 = row0 & 2047;
      if (which == 2) {                 // V^T: [bh][d][s], i-values are s-contiguous
        u16x4v pk;
        pk[0] = f2bf(v[0]); pk[1] = f2bf(v[1]); pk[2] = f2bf(v[2]); pk[3] = f2bf(v[3]);
        *(u16x4v*)((unsigned short*)C2 + ((size_t)bh * 128 + d) * 2048 + s0) = pk;
      } else {
        unsigned short* dst =
            (unsigned short*)(which ? C1 : C0) + ((size_t)bh * 2048 + s0) * 128 + d;
#pragma unroll
        for (int i2 = 0; i2 < 4; ++i2) dst[(size_t)i2 * 128] = f2bf(v[i2]);
      }
    }
  }
}

// ---------------- 128x128x(BK=64) bf16 GEMM (R2-proven, 3-4 blocks/CU) — out-proj ------
// fp32 epilogue C[row*N + col].
__global__ __launch_bounds__(256) void gemm_bt(
    const unsigned short* __restrict__ A, const unsigned short* __restrict__ B,
    float* __restrict__ C, int N, int Kd) {
  __shared__ unsigned short As[128 * 64];
  __shared__ unsigned short Bs[128 * 64];
  const int t = threadIdx.x;
  const int lane = t & 63, w = t >> 6;
  const int g = lane >> 4, c15 = lane & 15;
  const int wr = w >> 1, wc = w & 1;
  const int brow = blockIdx.y * 128, bcol = blockIdx.x * 128;
  const int srow = t >> 3;
  const int ssl = (t & 7) ^ (srow & 7);
  const unsigned short* pA = A + (size_t)(brow + srow) * Kd + ssl * 8;
  const unsigned short* pB = B + (size_t)(bcol + srow) * Kd + ssl * 8;

  int aoff[4][2], boff[4][2];
#pragma unroll
  for (int mi = 0; mi < 4; ++mi)
#pragma unroll
    for (int kk = 0; kk < 2; ++kk) {
      int arow = wr * 64 + mi * 16 + c15;
      int bcolr = wc * 64 + mi * 16 + c15;
      int p = (kk * 4 + g) ^ (c15 & 7);
      aoff[mi][kk] = arow * 128 + (p << 4);
      boff[mi][kk] = bcolr * 128 + (p << 4);
    }
  f32x4 zero4 = {0.f, 0.f, 0.f, 0.f};
  f32x4 acc[4][4];
#pragma unroll
  for (int a_ = 0; a_ < 4; ++a_)
#pragma unroll
    for (int b_ = 0; b_ < 4; ++b_) acc[a_][b_] = zero4;

  const int nk = Kd >> 6;
  for (int kt = 0; kt < nk; ++kt) {
    const unsigned short* a0 = pA + kt * 64;
    const unsigned short* b0 = pB + kt * 64;
#pragma unroll
    for (int c = 0; c < 4; ++c) {
      gld16((char*)As + c * 4096 + t * 16, a0 + (size_t)c * 32 * Kd);
      gld16((char*)Bs + c * 4096 + t * 16, b0 + (size_t)c * 32 * Kd);
    }
    __syncthreads();
    bf16x8 af[4][2], bfv[4][2];
#pragma unroll
    for (int mi = 0; mi < 4; ++mi)
#pragma unroll
      for (int kk = 0; kk < 2; ++kk) {
        af[mi][kk] = *(const bf16x8*)((const char*)As + aoff[mi][kk]);
        bfv[mi][kk] = *(const bf16x8*)((const char*)Bs + boff[mi][kk]);
      }
#pragma unroll
    for (int mi = 0; mi < 4; ++mi)
#pragma unroll
      for (int nj = 0; nj < 4; ++nj)
#pragma unroll
        for (int kk = 0; kk < 2; ++kk)
          acc[mi][nj] = __builtin_amdgcn_mfma_f32_16x16x32_bf16(
              af[mi][kk], bfv[nj][kk], acc[mi][nj], 0, 0, 0);
    __syncthreads();
  }
#pragma unroll
  for (int mi = 0; mi < 4; ++mi)
#pragma unroll
    for (int nj = 0; nj < 4; ++nj) {
      f32x4 v = acc[mi][nj];
      int row0 = brow + wr * 64 + mi * 16 + g * 4;
      int colc = bcol + wc * 64 + nj * 16 + c15;
#pragma unroll
      for (int i = 0; i < 4; ++i) C[(size_t)(row0 + i) * N + colc] = v[i];
    }
}

// ---------------- RoPE (in-place on bf16 Q,K [BH][S][128]); Q gets 1/sqrt(128) folded ----
__global__ __launch_bounds__(256) void rope_apply(
    unsigned short* __restrict__ Q, unsigned short* __restrict__ K,
    const float* __restrict__ ct, const float* __restrict__ st) {
  int id = blockIdx.x * 256 + threadIdx.x;  // 524288 = 32*2048*8
  int o = id & 7;
  int s = (id >> 3) & 2047;
  int bh = id >> 14;
  size_t base = ((size_t)bh * 2048 + s) * 128 + o * 8;
  u16x8v qlo = *(u16x8v*)(Q + base), qhi = *(u16x8v*)(Q + base + 64);
  u16x8v klo = *(u16x8v*)(K + base), khi = *(u16x8v*)(K + base + 64);
  const float* cp = ct + s * 64 + o * 8;
  const float* sp = st + s * 64 + o * 8;
#pragma unroll
  for (int j = 0; j < 8; ++j) {
    float c = cp[j], sn = sp[j];
    float ql = bf2f(qlo[j]), qh = bf2f(qhi[j]);
    qlo[j] = f2bf((ql * c - qh * sn) * SCALE_Q);
    qhi[j] = f2bf((qh * c + ql * sn) * SCALE_Q);
    float kl = bf2f(klo[j]), kh = bf2f(khi[j]);
    klo[j] = f2bf(kl * c - kh * sn);
    khi[j] = f2bf(kh * c + kl * sn);
  }
  *(u16x8v*)(Q + base) = qlo; *(u16x8v*)(Q + base + 64) = qhi;
  *(u16x8v*)(K + base) = klo; *(u16x8v*)(K + base + 64) = khi;
}

// ---------------- causal flash attention: paired q-blocks + dbuf K/V (unchanged) --------
__global__ __launch_bounds__(256) void attn_fwd(
    const unsigned short* __restrict__ Qg, const unsigned short* __restrict__ Kg,
    const unsigned short* __restrict__ Vtg, unsigned short* __restrict__ Og) {
  __shared__ unsigned short Ks[2][64 * 128];
  __shared__ unsigned short Vs[2][64 * 128];
  __shared__ unsigned short Pl[4][16 * 88];
  const int t = threadIdx.x;
  const int lane = t & 63, w = t >> 6;
  const int g = lane >> 4, c15 = lane & 15;
  const int pair = blockIdx.x;
  const int bh = blockIdx.y;
  const int b = bh >> 4, h = bh & 15;

  const int ksrow = t >> 4;
  const int kssl = (t & 15) ^ ksrow;
  const unsigned short* kp = Kg + ((size_t)bh * 2048 + ksrow) * 128 + kssl * 8;
  const int vsrow = t >> 3;
  const int vssl = (t & 7) ^ (vsrow & 7);
  const unsigned short* vp = Vtg + ((size_t)bh * 128 + vsrow) * 2048 + vssl * 8;

  auto stageTile = [&](int buf, int tkv) {
#pragma unroll
    for (int c = 0; c < 4; ++c) {
      gld16((char*)Ks[buf] + c * 4096 + t * 16, kp + (size_t)(tkv * 64 + c * 16) * 128);
      gld16((char*)Vs[buf] + c * 4096 + t * 16, vp + (size_t)c * 32 * 2048 + tkv * 64);
    }
  };

  f32x4 zero4 = {0.f, 0.f, 0.f, 0.f};
  f32x4 o[8];
  float mrow[4], lrow[4];
  bf16x8 qf[4];

  auto computeTile = [&](int buf, int qb, int tkv) {
    const int q0 = qb * 64;
    const int qrow = q0 + w * 16;
    f32x4 sv[4];
    __builtin_amdgcn_s_setprio(1);
#pragma unroll
    for (int cb = 0; cb < 4; ++cb) {
      f32x4 z = zero4;
#pragma unroll
      for (int kf = 0; kf < 4; ++kf) {
        int rowk = cb * 16 + c15;
        int p = (kf * 4 + g) ^ c15;
        bf16x8 kfr = *(const bf16x8*)((const char*)Ks[buf] + rowk * 256 + p * 16);
        z = __builtin_amdgcn_mfma_f32_16x16x32_bf16(qf[kf], kfr, z, 0, 0, 0);
      }
      sv[cb] = z;
    }
    __builtin_amdgcn_s_setprio(0);
    if (tkv == qb) {
#pragma unroll
      for (int cb = 0; cb < 4; ++cb)
#pragma unroll
        for (int i = 0; i < 4; ++i) {
          int colk = q0 + cb * 16 + c15;
          int rq = qrow + g * 4 + i;
          if (colk > rq) sv[cb][i] = -1e30f;
        }
    }
    float pmx[4];
#pragma unroll
    for (int i = 0; i < 4; ++i)
      pmx[i] = fmaxf(fmaxf(sv[0][i], sv[1][i]), fmaxf(sv[2][i], sv[3][i]));
#pragma unroll
    for (int dd = 1; dd < 16; dd <<= 1)
#pragma unroll
      for (int i = 0; i < 4; ++i) pmx[i] = fmaxf(pmx[i], __shfl_xor(pmx[i], dd));
    float sc[4], psum[4];
#pragma unroll
    for (int i = 0; i < 4; ++i) {
      float nm = fmaxf(mrow[i], pmx[i]);
      sc[i] = __expf(mrow[i] - nm);
      mrow[i] = nm;
      psum[i] = 0.f;
    }
#pragma unroll
    for (int cb = 0; cb < 4; ++cb)
#pragma unroll
      for (int i = 0; i < 4; ++i) {
        float e = __expf(sv[cb][i] - mrow[i]);
        sv[cb][i] = e;
        psum[i] += e;
      }
#pragma unroll
    for (int dd = 1; dd < 16; dd <<= 1)
#pragma unroll
      for (int i = 0; i < 4; ++i) psum[i] += __shfl_xor(psum[i], dd);
#pragma unroll
    for (int i = 0; i < 4; ++i) lrow[i] = lrow[i] * sc[i] + psum[i];
#pragma unroll
    for (int db = 0; db < 8; ++db)
#pragma unroll
      for (int i = 0; i < 4; ++i) o[db][i] *= sc[i];

    unsigned short* pw = &Pl[w][0];
#pragma unroll
    for (int cb = 0; cb < 4; ++cb)
#pragma unroll
      for (int i = 0; i < 4; ++i)
        pw[(g * 4 + i) * 88 + cb * 16 + c15] = f2bf(sv[cb][i]);
    bf16x8 pf[2];
#pragma unroll
    for (int kb = 0; kb < 2; ++kb)
      pf[kb] = *(const bf16x8*)((const char*)pw + c15 * 176 + kb * 64 + g * 16);

    __builtin_amdgcn_s_setprio(1);
#pragma unroll
    for (int db = 0; db < 8; ++db) {
#pragma unroll
      for (int kb = 0; kb < 2; ++kb) {
        int rowv = db * 16 + c15;
        int p = (kb * 4 + g) ^ (c15 & 7);
        bf16x8 vfr = *(const bf16x8*)((const char*)Vs[buf] + rowv * 128 + p * 16);
        o[db] = __builtin_amdgcn_mfma_f32_16x16x32_bf16(pf[kb], vfr, o[db], 0, 0, 0);
      }
    }
    __builtin_amdgcn_s_setprio(0);
  };

  auto loadQ = [&](int qb) {
    const unsigned short* qp = Qg + ((size_t)bh * 2048 + qb * 64 + w * 16 + c15) * 128 + g * 8;
#pragma unroll
    for (int kf = 0; kf < 4; ++kf) qf[kf] = *(const bf16x8*)(qp + kf * 32);
#pragma unroll
    for (int db = 0; db < 8; ++db) o[db] = zero4;
#pragma unroll
    for (int i = 0; i < 4; ++i) { mrow[i] = -1e30f; lrow[i] = 0.f; }
  };

  auto writeO = [&](int qb) {
    float linv[4];
#pragma unroll
    for (int i = 0; i < 4; ++i) linv[i] = 1.0f / lrow[i];
#pragma unroll
    for (int db = 0; db < 8; ++db)
#pragma unroll
      for (int i = 0; i < 4; ++i) {
        int q = qb * 64 + w * 16 + g * 4 + i;
        Og[((size_t)(b * 2048 + q)) * 2048 + h * 128 + db * 16 + c15] =
            f2bf(o[db][i] * linv[i]);
      }
  };

  const int qbA = pair, qbB = 31 - pair;
  const int ntA = qbA + 1, ntB = qbB + 1;
  int cur = 0;

  stageTile(0, 0);
  loadQ(qbA);
  for (int tkv = 0; tkv < ntA; ++tkv) {
    __syncthreads();
    if (tkv + 1 < ntA) stageTile(cur ^ 1, tkv + 1);
    else               stageTile(cur ^ 1, 0);
    computeTile(cur, qbA, tkv);
    cur ^= 1;
  }
  writeO(qbA);
  loadQ(qbB);
  for (int tkv = 0; tkv < ntB; ++tkv) {
    __syncthreads();
    if (tkv + 1 < ntB) stageTile(cur ^ 1, tkv + 1);
    computeTile(cur, qbB, tkv);
    cur ^= 1;
  }
  writeO(qbB);
}

extern "C" void kernel_launch(void* const* d_in, const int* in_sizes, int n_in,
                              void* d_out, int out_size, void* d_ws, size_t ws_size,
                              hipStream_t stream) {
  const float* x  = (const float*)d_in[0];
  const float* Wq = (const float*)d_in[1];
  const float* Wk = (const float*)d_in[2];
  const float* Wv = (const float*)d_in[3];
  const float* Wo = (const float*)d_in[4];
  char* p = (char*)d_ws;
  unsigned short* xb    = (unsigned short*)p;                 // 16 MB (reused as Ao)
  unsigned short* wqkvb = (unsigned short*)(p + 16777216);    // 24 MB
  unsigned short* wob   = (unsigned short*)(p + 41943040);    //  8 MB
  unsigned short* Qb    = (unsigned short*)(p + 50331648);    // 16 MB
  unsigned short* Kb    = (unsigned short*)(p + 67108864);    // 16 MB
  unsigned short* Vt    = (unsigned short*)(p + 83886080);    // 16 MB
  float* ctab           = (float*)(p + 100663296);            // 0.5 MB
  float* stab           = (float*)(p + 101187584);            // 0.5 MB -> end 101711872
  unsigned short* Ao = xb;  // xb dead after gemm_qkv

  cvt_all<<<dim3(4096, 5), 256, 0, stream>>>(x, Wq, Wk, Wv, Wo, xb, wqkvb, wob);
  rope_table<<<512, 256, 0, stream>>>(ctab, stab);
  gemm8p2<<<384, 512, 0, stream>>>(xb, wqkvb, Qb, Kb, Vt, 6144, 2048, 24);
  rope_apply<<<2048, 256, 0, stream>>>(Qb, Kb, ctab, stab);
  attn_fwd<<<dim3(16, 32), 256, 0, stream>>>(Qb, Kb, Vt, Ao);
  gemm_bt<<<dim3(16, 32), 256, 0, stream>>>(Ao, wob, (float*)d_out, 2048, 2048);
}

// Round 10
// 283.513 us; speedup vs baseline: 1.1236x; 1.0479x over previous
//
#include <hip/hip_runtime.h>
#include <stdint.h>

// Pipeline: cvt(fp32->bf16)
//   -> gemm_qk: x@[Wq;Wk] (N=4096), 256^2 tiles, grid 16x16=256 = EXACTLY one round
//   -> gemm_v : x@Wv (N=2048), 128x256 tiles, grid 32x8=256 = one round
//   -> rope tables -> rope(Q,K) -> causal flash attention (paired q-blocks, dbuf)
//   -> gemm_bt out-proj (128^2, 512 blocks = 2 uniform rounds, proven 37us).
// R10 insight: grid=384 over 256 CUs = 1.5 rounds quantized to 2 (R2..R9 all ~148us).
// Two exactly-256-block kernels make every round full: ~70 + ~37 = ~107us.

#define SCALE_Q 0.08838834764831845f

typedef short bf16x8 __attribute__((ext_vector_type(8)));
typedef float f32x4 __attribute__((ext_vector_type(4)));
typedef unsigned short u16x4v __attribute__((ext_vector_type(4)));
typedef unsigned short u16x8v __attribute__((ext_vector_type(8)));

__device__ __forceinline__ unsigned short f2bf(float f) {
  unsigned u = __float_as_uint(f);
  return (unsigned short)((u + 0x7FFFu + ((u >> 16) & 1u)) >> 16);  // RNE
}
__device__ __forceinline__ float bf2f(unsigned short h) {
  return __uint_as_float(((unsigned)h) << 16);
}
__device__ __forceinline__ void gld16(void* lds, const void* g) {
  __builtin_amdgcn_global_load_lds(
      (const __attribute__((address_space(1))) unsigned int*)g,
      (__attribute__((address_space(3))) unsigned int*)lds, 16, 0, 0);
}

// ---------------- fp32 -> bf16 conversion (5 regions via blockIdx.y) ----------------
__global__ __launch_bounds__(256) void cvt_all(
    const float* __restrict__ x, const float* __restrict__ wq,
    const float* __restrict__ wk, const float* __restrict__ wv,
    const float* __restrict__ wo,
    unsigned short* __restrict__ xb, unsigned short* __restrict__ wqkv,
    unsigned short* __restrict__ wob) {
  int r = blockIdx.y;
  size_t i = ((size_t)blockIdx.x * 256 + threadIdx.x) * 8;
  const float* src; unsigned short* dst; size_t n;
  if (r == 0)      { src = x;  dst = xb;             n = 8388608; }
  else if (r == 1) { src = wq; dst = wqkv;           n = 4194304; }
  else if (r == 2) { src = wk; dst = wqkv + 4194304; n = 4194304; }
  else if (r == 3) { src = wv; dst = wqkv + 8388608; n = 4194304; }
  else             { src = wo; dst = wob;            n = 4194304; }
  if (i >= n) return;
  float4 a = *(const float4*)(src + i);
  float4 b = *(const float4*)(src + i + 4);
  u16x8v o;
  o[0] = f2bf(a.x); o[1] = f2bf(a.y); o[2] = f2bf(a.z); o[3] = f2bf(a.w);
  o[4] = f2bf(b.x); o[5] = f2bf(b.y); o[6] = f2bf(b.z); o[7] = f2bf(b.w);
  *(u16x8v*)(dst + i) = o;
}

// ---------------- RoPE tables ----------------
__global__ __launch_bounds__(256) void rope_table(float* __restrict__ ct, float* __restrict__ st) {
  int id = blockIdx.x * 256 + threadIdx.x;  // 131072 = 2048*64
  int s = id >> 6, j = id & 63;
  float inv = __powf(10000.0f, -(float)j * (1.0f / 64.0f));
  float a = (float)s * inv;
  ct[id] = __cosf(a);
  st[id] = __sinf(a);
}

// ---------------- gemm_qk: 256x256x32, 4-deep ring (128KB), grid 16x16=256 ----------------
// C = A[4096][2048] @ B[4096][2048]^T; cols 0-2047 -> Q, 2048-4095 -> K, both [BH][S][128].
// 512 threads, 8 waves (wm 0..1, wn 0..3), wave tile 128x64. R6-proven body.
// LDS buffer: A 16KB packed [128 ldsrows][128B] (ldsrow L = A-rows L and L+128;
// slots 0-3 = row L k-chunks, 4-7 = row L+128), swz phys = slot ^ (L&7). B same.
__global__ __launch_bounds__(512, 2) void gemm_qk(
    const unsigned short* __restrict__ A, const unsigned short* __restrict__ B,
    unsigned short* __restrict__ Qo, unsigned short* __restrict__ Ko, int Kd) {
  __shared__ unsigned short As[4][128 * 64];   // 4 x 16KB
  __shared__ unsigned short Bs[4][128 * 64];   // 4 x 16KB
  const int t = threadIdx.x;
  const int lane = t & 63, w = t >> 6;
  const int g = lane >> 4, c15 = lane & 15;
  const int wm = w >> 2, wn = w & 3;

  // XCD chunk: chunk = bid&7 owns 16 rows x 2 cols, col-major within chunk.
  const int chunk = (int)blockIdx.x & 7;
  const int idx = (int)blockIdx.x >> 3;       // 0..31
  const int row = idx & 15;
  const int col = chunk * 2 + (idx >> 4);
  const int brow = row * 256, bcol = col * 256;

  const int l = t >> 3;
  const int lg = (t & 7) ^ (l & 7);
  const unsigned short* srcA = A + (size_t)(brow + l + ((lg >> 2) << 7)) * Kd + (lg & 3) * 8;
  const unsigned short* srcB = B + (size_t)(bcol + l + ((lg >> 2) << 7)) * Kd + (lg & 3) * 8;

  auto stage = [&](int kt) {
    const int buf = kt & 3;
    const unsigned short* a = srcA + kt * 32;
    const unsigned short* b = srcB + kt * 32;
    gld16((char*)As[buf] + t * 16, a);
    gld16((char*)As[buf] + 8192 + t * 16, a + (size_t)64 * Kd);
    gld16((char*)Bs[buf] + t * 16, b);
    gld16((char*)Bs[buf] + 8192 + t * 16, b + (size_t)64 * Kd);
  };

  const int aoff = c15 * 128 + ((((wm << 2) | g) ^ (c15 & 7)) << 4);
  const int boff = ((wn & 1) << 13) + c15 * 128 + (((((wn >> 1) << 2) | g) ^ (c15 & 7)) << 4);

  f32x4 zero4 = {0.f, 0.f, 0.f, 0.f};
  f32x4 acc[8][4];
#pragma unroll
  for (int a_ = 0; a_ < 8; ++a_)
#pragma unroll
    for (int b_ = 0; b_ < 4; ++b_) acc[a_][b_] = zero4;

  const int nk = Kd >> 5;  // 64
  stage(0); stage(1); stage(2);
  asm volatile("s_waitcnt vmcnt(8)" ::: "memory");   // stage(0)'s 4 loads landed
  __builtin_amdgcn_s_barrier();

  for (int kt = 0; kt < nk; ++kt) {
    const char* ab = (const char*)As[kt & 3];
    const char* bb = (const char*)Bs[kt & 3];
    bf16x8 bfv[4], af0[4], af1[4];
#pragma unroll
    for (int nj = 0; nj < 4; ++nj) bfv[nj] = *(const bf16x8*)(bb + boff + nj * 2048);
#pragma unroll
    for (int mi = 0; mi < 4; ++mi) af0[mi] = *(const bf16x8*)(ab + aoff + mi * 2048);
    __builtin_amdgcn_sched_barrier(0);          // pin issue order: bfv+af0 before af1
#pragma unroll
    for (int mi = 0; mi < 4; ++mi) af1[mi] = *(const bf16x8*)(ab + aoff + (mi + 4) * 2048);
    if (kt + 3 < nk) stage(kt + 3);             // overwrites buf[(kt-1)&3] — safe per barrier@kt-1
    asm volatile("s_waitcnt lgkmcnt(4)" ::: "memory");  // bfv+af0 done; af1 in flight
    __builtin_amdgcn_sched_barrier(0);
    __builtin_amdgcn_s_setprio(1);
#pragma unroll
    for (int mi = 0; mi < 4; ++mi)
#pragma unroll
      for (int nj = 0; nj < 4; ++nj)
        acc[mi][nj] = __builtin_amdgcn_mfma_f32_16x16x32_bf16(
            af0[mi], bfv[nj], acc[mi][nj], 0, 0, 0);
    __builtin_amdgcn_s_setprio(0);
    asm volatile("s_waitcnt lgkmcnt(0)" ::: "memory");  // af1 done
    __builtin_amdgcn_sched_barrier(0);
    __builtin_amdgcn_s_setprio(1);
#pragma unroll
    for (int mi = 0; mi < 4; ++mi)
#pragma unroll
      for (int nj = 0; nj < 4; ++nj)
        acc[mi + 4][nj] = __builtin_amdgcn_mfma_f32_16x16x32_bf16(
            af1[mi], bfv[nj], acc[mi + 4][nj], 0, 0, 0);
    __builtin_amdgcn_s_setprio(0);
    if (kt + 3 < nk) {
      asm volatile("s_waitcnt vmcnt(8)" ::: "memory");   // stage(kt+1) landed; kt+2,kt+3 fly
    } else if (kt + 2 < nk) {
      asm volatile("s_waitcnt vmcnt(4)" ::: "memory");
    } else if (kt + 1 < nk) {
      asm volatile("s_waitcnt vmcnt(0)" ::: "memory");
    }
    __builtin_amdgcn_s_barrier();               // publish buf[kt+1]; close reads of buf[kt]
  }

  // Epilogue: Q/K scatter. C/D layout: col = lane&15, row = (lane>>4)*4 + i  [m89]
#pragma unroll
  for (int mi = 0; mi < 8; ++mi) {
#pragma unroll
    for (int nj = 0; nj < 4; ++nj) {
      f32x4 v = acc[mi][nj];
      int row0 = brow + wm * 128 + mi * 16 + g * 4;
      int colc = bcol + wn * 64 + nj * 16 + c15;
      int which = colc >> 11;           // 0=Q 1=K
      int hc = colc & 2047;
      int bh = ((row0 >> 11) << 4) + (hc >> 7);
      int d = hc & 127, s0 = row0 & 2047;
      unsigned short* dst =
          (which ? Ko : Qo) + ((size_t)bh * 2048 + s0) * 128 + d;
#pragma unroll
      for (int i2 = 0; i2 < 4; ++i2) dst[(size_t)i2 * 128] = f2bf(v[i2]);
    }
  }
}

// ---------------- gemm_v: 128x256x32, 4-deep ring (96KB), grid 32x8=256 ----------------
// C = A[4096][2048] @ Wv[2048][2048]^T -> V^T [BH][128][S].
// 512 threads, 8 waves (wm 0..1, wn 0..3), wave tile 64x64, acc[4][4].
// A-LDS: 8KB packed [64 ldsrows][128B] (ldsrow L = A-rows L and L+64). B-LDS as gemm_qk.
__global__ __launch_bounds__(512, 2) void gemm_v(
    const unsigned short* __restrict__ A, const unsigned short* __restrict__ B,
    unsigned short* __restrict__ Vt, int Kd) {
  __shared__ unsigned short As[4][64 * 64];    // 4 x 8KB
  __shared__ unsigned short Bs[4][128 * 64];   // 4 x 16KB
  const int t = threadIdx.x;
  const int lane = t & 63, w = t >> 6;
  const int g = lane >> 4, c15 = lane & 15;
  const int wm = w >> 2, wn = w & 3;

  // XCD chunk: chunk = bid&7 owns 4 row-tiles x all 8 cols (row-major within chunk).
  const int chunk = (int)blockIdx.x & 7;
  const int idx = (int)blockIdx.x >> 3;       // 0..31
  const int row = chunk * 4 + (idx >> 3);
  const int col = idx & 7;
  const int brow = row * 128, bcol = col * 256;

  const int l = t >> 3;
  const int lg = (t & 7) ^ (l & 7);
  // A: ldsrow l in 0..63 holds A-rows l and l+64 (slots 0-3 / 4-7)
  const unsigned short* srcA = A + (size_t)(brow + l + ((lg >> 2) << 6)) * Kd + (lg & 3) * 8;
  const unsigned short* srcB = B + (size_t)(bcol + l + ((lg >> 2) << 7)) * Kd + (lg & 3) * 8;

  auto stage = [&](int kt) {
    const int buf = kt & 3;
    const unsigned short* a = srcA + kt * 32;
    const unsigned short* b = srcB + kt * 32;
    gld16((char*)As[buf] + t * 16, a);                           // all 64 ldsrows
    gld16((char*)Bs[buf] + t * 16, b);
    gld16((char*)Bs[buf] + 8192 + t * 16, b + (size_t)64 * Kd);
  };

  // wave tile 64x64: A rows wm*64+mi*16+c15 (ldsrow mi*16+c15, half=wm)
  const int aoff = c15 * 128 + ((((wm << 2) | g) ^ (c15 & 7)) << 4);
  const int boff = ((wn & 1) << 13) + c15 * 128 + (((((wn >> 1) << 2) | g) ^ (c15 & 7)) << 4);

  f32x4 zero4 = {0.f, 0.f, 0.f, 0.f};
  f32x4 acc[4][4];
#pragma unroll
  for (int a_ = 0; a_ < 4; ++a_)
#pragma unroll
    for (int b_ = 0; b_ < 4; ++b_) acc[a_][b_] = zero4;

  const int nk = Kd >> 5;  // 64
  stage(0); stage(1); stage(2);
  asm volatile("s_waitcnt vmcnt(6)" ::: "memory");   // stage(0)'s 3 loads landed
  __builtin_amdgcn_s_barrier();

  for (int kt = 0; kt < nk; ++kt) {
    const char* ab = (const char*)As[kt & 3];
    const char* bb = (const char*)Bs[kt & 3];
    bf16x8 bfv[4], af0[2], af1[2];
#pragma unroll
    for (int nj = 0; nj < 4; ++nj) bfv[nj] = *(const bf16x8*)(bb + boff + nj * 2048);
#pragma unroll
    for (int mi = 0; mi < 2; ++mi) af0[mi] = *(const bf16x8*)(ab + aoff + mi * 2048);
    __builtin_amdgcn_sched_barrier(0);
#pragma unroll
    for (int mi = 0; mi < 2; ++mi) af1[mi] = *(const bf16x8*)(ab + aoff + (mi + 2) * 2048);
    if (kt + 3 < nk) stage(kt + 3);
    asm volatile("s_waitcnt lgkmcnt(2)" ::: "memory");  // bfv+af0 done; af1 in flight
    __builtin_amdgcn_sched_barrier(0);
    __builtin_amdgcn_s_setprio(1);
#pragma unroll
    for (int mi = 0; mi < 2; ++mi)
#pragma unroll
      for (int nj = 0; nj < 4; ++nj)
        acc[mi][nj] = __builtin_amdgcn_mfma_f32_16x16x32_bf16(
            af0[mi], bfv[nj], acc[mi][nj], 0, 0, 0);
    __builtin_amdgcn_s_setprio(0);
    asm volatile("s_waitcnt lgkmcnt(0)" ::: "memory");
    __builtin_amdgcn_sched_barrier(0);
    __builtin_amdgcn_s_setprio(1);
#pragma unroll
    for (int mi = 0; mi < 2; ++mi)
#pragma unroll
      for (int nj = 0; nj < 4; ++nj)
        acc[mi + 2][nj] = __builtin_amdgcn_mfma_f32_16x16x32_bf16(
            af1[mi], bfv[nj], acc[mi + 2][nj], 0, 0, 0);
    __builtin_amdgcn_s_setprio(0);
    if (kt + 3 < nk) {
      asm volatile("s_waitcnt vmcnt(6)" ::: "memory");
    } else if (kt + 3 == nk) {
      asm volatile("s_waitcnt vmcnt(3)" ::: "memory");
    } else if (kt + 2 == nk) {
      asm volatile("s_waitcnt vmcnt(0)" ::: "memory");
    }
    __builtin_amdgcn_s_barrier();
  }

  // Epilogue: V^T scatter [bh][d][s] (i-values s-contiguous)
#pragma unroll
  for (int mi = 0; mi < 4; ++mi) {
#pragma unroll
    for (int nj = 0; nj < 4; ++nj) {
      f32x4 v = acc[mi][nj];
      int row0 = brow + wm * 64 + mi * 16 + g * 4;
      int colc = bcol + wn * 64 + nj * 16 + c15;
      int bh = ((row0 >> 11) << 4) + (colc >> 7);
      int d = colc & 127, s0 = row0 & 2047;
      u16x4v pk;
      pk[0] = f2bf(v[0]); pk[1] = f2bf(v[1]); pk[2] = f2bf(v[2]); pk[3] = f2bf(v[3]);
      *(u16x4v*)(Vt + ((size_t)bh * 128 + d) * 2048 + s0) = pk;
    }
  }
}

// ---------------- 128x128x(BK=64) bf16 GEMM (R2-proven) — out-proj ------
__global__ __launch_bounds__(256) void gemm_bt(
    const unsigned short* __restrict__ A, const unsigned short* __restrict__ B,
    float* __restrict__ C, int N, int Kd) {
  __shared__ unsigned short As[128 * 64];
  __shared__ unsigned short Bs[128 * 64];
  const int t = threadIdx.x;
  const int lane = t & 63, w = t >> 6;
  const int g = lane >> 4, c15 = lane & 15;
  const int wr = w >> 1, wc = w & 1;
  const int brow = blockIdx.y * 128, bcol = blockIdx.x * 128;
  const int srow = t >> 3;
  const int ssl = (t & 7) ^ (srow & 7);
  const unsigned short* pA = A + (size_t)(brow + srow) * Kd + ssl * 8;
  const unsigned short* pB = B + (size_t)(bcol + srow) * Kd + ssl * 8;

  int aoff[4][2], boff[4][2];
#pragma unroll
  for (int mi = 0; mi < 4; ++mi)
#pragma unroll
    for (int kk = 0; kk < 2; ++kk) {
      int arow = wr * 64 + mi * 16 + c15;
      int bcolr = wc * 64 + mi * 16 + c15;
      int p = (kk * 4 + g) ^ (c15 & 7);
      aoff[mi][kk] = arow * 128 + (p << 4);
      boff[mi][kk] = bcolr * 128 + (p << 4);
    }
  f32x4 zero4 = {0.f, 0.f, 0.f, 0.f};
  f32x4 acc[4][4];
#pragma unroll
  for (int a_ = 0; a_ < 4; ++a_)
#pragma unroll
    for (int b_ = 0; b_ < 4; ++b_) acc[a_][b_] = zero4;

  const int nk = Kd >> 6;
  for (int kt = 0; kt < nk; ++kt) {
    const unsigned short* a0 = pA + kt * 64;
    const unsigned short* b0 = pB + kt * 64;
#pragma unroll
    for (int c = 0; c < 4; ++c) {
      gld16((char*)As + c * 4096 + t * 16, a0 + (size_t)c * 32 * Kd);
      gld16((char*)Bs + c * 4096 + t * 16, b0 + (size_t)c * 32 * Kd);
    }
    __syncthreads();
    bf16x8 af[4][2], bfv[4][2];
#pragma unroll
    for (int mi = 0; mi < 4; ++mi)
#pragma unroll
      for (int kk = 0; kk < 2; ++kk) {
        af[mi][kk] = *(const bf16x8*)((const char*)As + aoff[mi][kk]);
        bfv[mi][kk] = *(const bf16x8*)((const char*)Bs + boff[mi][kk]);
      }
#pragma unroll
    for (int mi = 0; mi < 4; ++mi)
#pragma unroll
      for (int nj = 0; nj < 4; ++nj)
#pragma unroll
        for (int kk = 0; kk < 2; ++kk)
          acc[mi][nj] = __builtin_amdgcn_mfma_f32_16x16x32_bf16(
              af[mi][kk], bfv[nj][kk], acc[mi][nj], 0, 0, 0);
    __syncthreads();
  }
#pragma unroll
  for (int mi = 0; mi < 4; ++mi)
#pragma unroll
    for (int nj = 0; nj < 4; ++nj) {
      f32x4 v = acc[mi][nj];
      int row0 = brow + wr * 64 + mi * 16 + g * 4;
      int colc = bcol + wc * 64 + nj * 16 + c15;
#pragma unroll
      for (int i = 0; i < 4; ++i) C[(size_t)(row0 + i) * N + colc] = v[i];
    }
}

// ---------------- RoPE (in-place on bf16 Q,K [BH][S][128]); Q gets 1/sqrt(128) folded ----
__global__ __launch_bounds__(256) void rope_apply(
    unsigned short* __restrict__ Q, unsigned short* __restrict__ K,
    const float* __restrict__ ct, const float* __restrict__ st) {
  int id = blockIdx.x * 256 + threadIdx.x;  // 524288 = 32*2048*8
  int o = id & 7;
  int s = (id >> 3) & 2047;
  int bh = id >> 14;
  size_t base = ((size_t)bh * 2048 + s) * 128 + o * 8;
  u16x8v qlo = *(u16x8v*)(Q + base), qhi = *(u16x8v*)(Q + base + 64);
  u16x8v klo = *(u16x8v*)(K + base), khi = *(u16x8v*)(K + base + 64);
  const float* cp = ct + s * 64 + o * 8;
  const float* sp = st + s * 64 + o * 8;
#pragma unroll
  for (int j = 0; j < 8; ++j) {
    float c = cp[j], sn = sp[j];
    float ql = bf2f(qlo[j]), qh = bf2f(qhi[j]);
    qlo[j] = f2bf((ql * c - qh * sn) * SCALE_Q);
    qhi[j] = f2bf((qh * c + ql * sn) * SCALE_Q);
    float kl = bf2f(klo[j]), kh = bf2f(khi[j]);
    klo[j] = f2bf(kl * c - kh * sn);
    khi[j] = f2bf(kh * c + kl * sn);
  }
  *(u16x8v*)(Q + base) = qlo; *(u16x8v*)(Q + base + 64) = qhi;
  *(u16x8v*)(K + base) = klo; *(u16x8v*)(K + base + 64) = khi;
}

// ---------------- causal flash attention: paired q-blocks + dbuf K/V (unchanged) --------
__global__ __launch_bounds__(256) void attn_fwd(
    const unsigned short* __restrict__ Qg, const unsigned short* __restrict__ Kg,
    const unsigned short* __restrict__ Vtg, unsigned short* __restrict__ Og) {
  __shared__ unsigned short Ks[2][64 * 128];
  __shared__ unsigned short Vs[2][64 * 128];
  __shared__ unsigned short Pl[4][16 * 88];
  const int t = threadIdx.x;
  const int lane = t & 63, w = t >> 6;
  const int g = lane >> 4, c15 = lane & 15;
  const int pair = blockIdx.x;
  const int bh = blockIdx.y;
  const int b = bh >> 4, h = bh & 15;

  const int ksrow = t >> 4;
  const int kssl = (t & 15) ^ ksrow;
  const unsigned short* kp = Kg + ((size_t)bh * 2048 + ksrow) * 128 + kssl * 8;
  const int vsrow = t >> 3;
  const int vssl = (t & 7) ^ (vsrow & 7);
  const unsigned short* vp = Vtg + ((size_t)bh * 128 + vsrow) * 2048 + vssl * 8;

  auto stageTile = [&](int buf, int tkv) {
#pragma unroll
    for (int c = 0; c < 4; ++c) {
      gld16((char*)Ks[buf] + c * 4096 + t * 16, kp + (size_t)(tkv * 64 + c * 16) * 128);
      gld16((char*)Vs[buf] + c * 4096 + t * 16, vp + (size_t)c * 32 * 2048 + tkv * 64);
    }
  };

  f32x4 zero4 = {0.f, 0.f, 0.f, 0.f};
  f32x4 o[8];
  float mrow[4], lrow[4];
  bf16x8 qf[4];

  auto computeTile = [&](int buf, int qb, int tkv) {
    const int q0 = qb * 64;
    const int qrow = q0 + w * 16;
    f32x4 sv[4];
    __builtin_amdgcn_s_setprio(1);
#pragma unroll
    for (int cb = 0; cb < 4; ++cb) {
      f32x4 z = zero4;
#pragma unroll
      for (int kf = 0; kf < 4; ++kf) {
        int rowk = cb * 16 + c15;
        int p = (kf * 4 + g) ^ c15;
        bf16x8 kfr = *(const bf16x8*)((const char*)Ks[buf] + rowk * 256 + p * 16);
        z = __builtin_amdgcn_mfma_f32_16x16x32_bf16(qf[kf], kfr, z, 0, 0, 0);
      }
      sv[cb] = z;
    }
    __builtin_amdgcn_s_setprio(0);
    if (tkv == qb) {
#pragma unroll
      for (int cb = 0; cb < 4; ++cb)
#pragma unroll
        for (int i = 0; i < 4; ++i) {
          int colk = q0 + cb * 16 + c15;
          int rq = qrow + g * 4 + i;
          if (colk > rq) sv[cb][i] = -1e30f;
        }
    }
    float pmx[4];
#pragma unroll
    for (int i = 0; i < 4; ++i)
      pmx[i] = fmaxf(fmaxf(sv[0][i], sv[1][i]), fmaxf(sv[2][i], sv[3][i]));
#pragma unroll
    for (int dd = 1; dd < 16; dd <<= 1)
#pragma unroll
      for (int i = 0; i < 4; ++i) pmx[i] = fmaxf(pmx[i], __shfl_xor(pmx[i], dd));
    float sc[4], psum[4];
#pragma unroll
    for (int i = 0; i < 4; ++i) {
      float nm = fmaxf(mrow[i], pmx[i]);
      sc[i] = __expf(mrow[i] - nm);
      mrow[i] = nm;
      psum[i] = 0.f;
    }
#pragma unroll
    for (int cb = 0; cb < 4; ++cb)
#pragma unroll
      for (int i = 0; i < 4; ++i) {
        float e = __expf(sv[cb][i] - mrow[i]);
        sv[cb][i] = e;
        psum[i] += e;
      }
#pragma unroll
    for (int dd = 1; dd < 16; dd <<= 1)
#pragma unroll
      for (int i = 0; i < 4; ++i) psum[i] += __shfl_xor(psum[i], dd);
#pragma unroll
    for (int i = 0; i < 4; ++i) lrow[i] = lrow[i] * sc[i] + psum[i];
#pragma unroll
    for (int db = 0; db < 8; ++db)
#pragma unroll
      for (int i = 0; i < 4; ++i) o[db][i] *= sc[i];

    unsigned short* pw = &Pl[w][0];
#pragma unroll
    for (int cb = 0; cb < 4; ++cb)
#pragma unroll
      for (int i = 0; i < 4; ++i)
        pw[(g * 4 + i) * 88 + cb * 16 + c15] = f2bf(sv[cb][i]);
    bf16x8 pf[2];
#pragma unroll
    for (int kb = 0; kb < 2; ++kb)
      pf[kb] = *(const bf16x8*)((const char*)pw + c15 * 176 + kb * 64 + g * 16);

    __builtin_amdgcn_s_setprio(1);
#pragma unroll
    for (int db = 0; db < 8; ++db) {
#pragma unroll
      for (int kb = 0; kb < 2; ++kb) {
        int rowv = db * 16 + c15;
        int p = (kb * 4 + g) ^ (c15 & 7);
        bf16x8 vfr = *(const bf16x8*)((const char*)Vs[buf] + rowv * 128 + p * 16);
        o[db] = __builtin_amdgcn_mfma_f32_16x16x32_bf16(pf[kb], vfr, o[db], 0, 0, 0);
      }
    }
    __builtin_amdgcn_s_setprio(0);
  };

  auto loadQ = [&](int qb) {
    const unsigned short* qp = Qg + ((size_t)bh * 2048 + qb * 64 + w * 16 + c15) * 128 + g * 8;
#pragma unroll
    for (int kf = 0; kf < 4; ++kf) qf[kf] = *(const bf16x8*)(qp + kf * 32);
#pragma unroll
    for (int db = 0; db < 8; ++db) o[db] = zero4;
#pragma unroll
    for (int i = 0; i < 4; ++i) { mrow[i] = -1e30f; lrow[i] = 0.f; }
  };

  auto writeO = [&](int qb) {
    float linv[4];
#pragma unroll
    for (int i = 0; i < 4; ++i) linv[i] = 1.0f / lrow[i];
#pragma unroll
    for (int db = 0; db < 8; ++db)
#pragma unroll
      for (int i = 0; i < 4; ++i) {
        int q = qb * 64 + w * 16 + g * 4 + i;
        Og[((size_t)(b * 2048 + q)) * 2048 + h * 128 + db * 16 + c15] =
            f2bf(o[db][i] * linv[i]);
      }
  };

  const int qbA = pair, qbB = 31 - pair;
  const int ntA = qbA + 1, ntB = qbB + 1;
  int cur = 0;

  stageTile(0, 0);
  loadQ(qbA);
  for (int tkv = 0; tkv < ntA; ++tkv) {
    __syncthreads();
    if (tkv + 1 < ntA) stageTile(cur ^ 1, tkv + 1);
    else               stageTile(cur ^ 1, 0);
    computeTile(cur, qbA, tkv);
    cur ^= 1;
  }
  writeO(qbA);
  loadQ(qbB);
  for (int tkv = 0; tkv < ntB; ++tkv) {
    __syncthreads();
    if (tkv + 1 < ntB) stageTile(cur ^ 1, tkv + 1);
    computeTile(cur, qbB, tkv);
    cur ^= 1;
  }
  writeO(qbB);
}

extern "C" void kernel_launch(void* const* d_in, const int* in_sizes, int n_in,
                              void* d_out, int out_size, void* d_ws, size_t ws_size,
                              hipStream_t stream) {
  const float* x  = (const float*)d_in[0];
  const float* Wq = (const float*)d_in[1];
  const float* Wk = (const float*)d_in[2];
  const float* Wv = (const float*)d_in[3];
  const float* Wo = (const float*)d_in[4];
  char* p = (char*)d_ws;
  unsigned short* xb    = (unsigned short*)p;                 // 16 MB (reused as Ao)
  unsigned short* wqkvb = (unsigned short*)(p + 16777216);    // 24 MB
  unsigned short* wob   = (unsigned short*)(p + 41943040);    //  8 MB
  unsigned short* Qb    = (unsigned short*)(p + 50331648);    // 16 MB
  unsigned short* Kb    = (unsigned short*)(p + 67108864);    // 16 MB
  unsigned short* Vt    = (unsigned short*)(p + 83886080);    // 16 MB
  float* ctab           = (float*)(p + 100663296);            // 0.5 MB
  float* stab           = (float*)(p + 101187584);            // 0.5 MB -> end 101711872
  unsigned short* Ao = xb;  // xb dead after QKV gemms

  cvt_all<<<dim3(4096, 5), 256, 0, stream>>>(x, Wq, Wk, Wv, Wo, xb, wqkvb, wob);
  rope_table<<<512, 256, 0, stream>>>(ctab, stab);
  gemm_qk<<<256, 512, 0, stream>>>(xb, wqkvb, Qb, Kb, 2048);
  gemm_v<<<256, 512, 0, stream>>>(xb, wqkvb + (size_t)4096 * 2048, Vt, 2048);
  rope_apply<<<2048, 256, 0, stream>>>(Qb, Kb, ctab, stab);
  attn_fwd<<<dim3(16, 32), 256, 0, stream>>>(Qb, Kb, Vt, Ao);
  gemm_bt<<<dim3(16, 32), 256, 0, stream>>>(Ao, wob, (float*)d_out, 2048, 2048);
}

// Round 11
// 278.181 us; speedup vs baseline: 1.1452x; 1.0192x over previous
//
#include <hip/hip_runtime.h>
#include <stdint.h>

// Pipeline: cvt(fp32->bf16)
//   -> gemm_qk: x@[Wq;Wk] (N=4096), 256^2 tiles, grid 256 = one full round
//   -> gemm_v : x@Wv (N=2048), 128x256 tiles, grid 256 = one round
//   -> rope tables -> rope(Q,K)
//   -> attn_fwd R11: QBLK=128 (8 waves), KVB=64, grid 8x32=256 (1/CU, uniform 34 tiles),
//      counted-vmcnt dbuf (no __syncthreads vmcnt(0) drain), defer-max (T13, THR=8)
//   -> gemm_bt out-proj (128^2).

#define SCALE_Q 0.08838834764831845f

typedef short bf16x8 __attribute__((ext_vector_type(8)));
typedef float f32x4 __attribute__((ext_vector_type(4)));
typedef unsigned short u16x4v __attribute__((ext_vector_type(4)));
typedef unsigned short u16x8v __attribute__((ext_vector_type(8)));

__device__ __forceinline__ unsigned short f2bf(float f) {
  unsigned u = __float_as_uint(f);
  return (unsigned short)((u + 0x7FFFu + ((u >> 16) & 1u)) >> 16);  // RNE
}
__device__ __forceinline__ float bf2f(unsigned short h) {
  return __uint_as_float(((unsigned)h) << 16);
}
__device__ __forceinline__ void gld16(void* lds, const void* g) {
  __builtin_amdgcn_global_load_lds(
      (const __attribute__((address_space(1))) unsigned int*)g,
      (__attribute__((address_space(3))) unsigned int*)lds, 16, 0, 0);
}

// ---------------- fp32 -> bf16 conversion (5 regions via blockIdx.y) ----------------
__global__ __launch_bounds__(256) void cvt_all(
    const float* __restrict__ x, const float* __restrict__ wq,
    const float* __restrict__ wk, const float* __restrict__ wv,
    const float* __restrict__ wo,
    unsigned short* __restrict__ xb, unsigned short* __restrict__ wqkv,
    unsigned short* __restrict__ wob) {
  int r = blockIdx.y;
  size_t i = ((size_t)blockIdx.x * 256 + threadIdx.x) * 8;
  const float* src; unsigned short* dst; size_t n;
  if (r == 0)      { src = x;  dst = xb;             n = 8388608; }
  else if (r == 1) { src = wq; dst = wqkv;           n = 4194304; }
  else if (r == 2) { src = wk; dst = wqkv + 4194304; n = 4194304; }
  else if (r == 3) { src = wv; dst = wqkv + 8388608; n = 4194304; }
  else             { src = wo; dst = wob;            n = 4194304; }
  if (i >= n) return;
  float4 a = *(const float4*)(src + i);
  float4 b = *(const float4*)(src + i + 4);
  u16x8v o;
  o[0] = f2bf(a.x); o[1] = f2bf(a.y); o[2] = f2bf(a.z); o[3] = f2bf(a.w);
  o[4] = f2bf(b.x); o[5] = f2bf(b.y); o[6] = f2bf(b.z); o[7] = f2bf(b.w);
  *(u16x8v*)(dst + i) = o;
}

// ---------------- RoPE tables ----------------
__global__ __launch_bounds__(256) void rope_table(float* __restrict__ ct, float* __restrict__ st) {
  int id = blockIdx.x * 256 + threadIdx.x;  // 131072 = 2048*64
  int s = id >> 6, j = id & 63;
  float inv = __powf(10000.0f, -(float)j * (1.0f / 64.0f));
  float a = (float)s * inv;
  ct[id] = __cosf(a);
  st[id] = __sinf(a);
}

// ---------------- gemm_qk: 256x256x32, 4-deep ring (128KB), grid 16x16=256 ----------------
__global__ __launch_bounds__(512, 2) void gemm_qk(
    const unsigned short* __restrict__ A, const unsigned short* __restrict__ B,
    unsigned short* __restrict__ Qo, unsigned short* __restrict__ Ko, int Kd) {
  __shared__ unsigned short As[4][128 * 64];   // 4 x 16KB
  __shared__ unsigned short Bs[4][128 * 64];   // 4 x 16KB
  const int t = threadIdx.x;
  const int lane = t & 63, w = t >> 6;
  const int g = lane >> 4, c15 = lane & 15;
  const int wm = w >> 2, wn = w & 3;

  const int chunk = (int)blockIdx.x & 7;
  const int idx = (int)blockIdx.x >> 3;       // 0..31
  const int row = idx & 15;
  const int col = chunk * 2 + (idx >> 4);
  const int brow = row * 256, bcol = col * 256;

  const int l = t >> 3;
  const int lg = (t & 7) ^ (l & 7);
  const unsigned short* srcA = A + (size_t)(brow + l + ((lg >> 2) << 7)) * Kd + (lg & 3) * 8;
  const unsigned short* srcB = B + (size_t)(bcol + l + ((lg >> 2) << 7)) * Kd + (lg & 3) * 8;

  auto stage = [&](int kt) {
    const int buf = kt & 3;
    const unsigned short* a = srcA + kt * 32;
    const unsigned short* b = srcB + kt * 32;
    gld16((char*)As[buf] + t * 16, a);
    gld16((char*)As[buf] + 8192 + t * 16, a + (size_t)64 * Kd);
    gld16((char*)Bs[buf] + t * 16, b);
    gld16((char*)Bs[buf] + 8192 + t * 16, b + (size_t)64 * Kd);
  };

  const int aoff = c15 * 128 + ((((wm << 2) | g) ^ (c15 & 7)) << 4);
  const int boff = ((wn & 1) << 13) + c15 * 128 + (((((wn >> 1) << 2) | g) ^ (c15 & 7)) << 4);

  f32x4 zero4 = {0.f, 0.f, 0.f, 0.f};
  f32x4 acc[8][4];
#pragma unroll
  for (int a_ = 0; a_ < 8; ++a_)
#pragma unroll
    for (int b_ = 0; b_ < 4; ++b_) acc[a_][b_] = zero4;

  const int nk = Kd >> 5;  // 64
  stage(0); stage(1); stage(2);
  asm volatile("s_waitcnt vmcnt(8)" ::: "memory");
  __builtin_amdgcn_s_barrier();

  for (int kt = 0; kt < nk; ++kt) {
    const char* ab = (const char*)As[kt & 3];
    const char* bb = (const char*)Bs[kt & 3];
    bf16x8 bfv[4], af0[4], af1[4];
#pragma unroll
    for (int nj = 0; nj < 4; ++nj) bfv[nj] = *(const bf16x8*)(bb + boff + nj * 2048);
#pragma unroll
    for (int mi = 0; mi < 4; ++mi) af0[mi] = *(const bf16x8*)(ab + aoff + mi * 2048);
    __builtin_amdgcn_sched_barrier(0);
#pragma unroll
    for (int mi = 0; mi < 4; ++mi) af1[mi] = *(const bf16x8*)(ab + aoff + (mi + 4) * 2048);
    if (kt + 3 < nk) stage(kt + 3);
    asm volatile("s_waitcnt lgkmcnt(4)" ::: "memory");
    __builtin_amdgcn_sched_barrier(0);
    __builtin_amdgcn_s_setprio(1);
#pragma unroll
    for (int mi = 0; mi < 4; ++mi)
#pragma unroll
      for (int nj = 0; nj < 4; ++nj)
        acc[mi][nj] = __builtin_amdgcn_mfma_f32_16x16x32_bf16(
            af0[mi], bfv[nj], acc[mi][nj], 0, 0, 0);
    __builtin_amdgcn_s_setprio(0);
    asm volatile("s_waitcnt lgkmcnt(0)" ::: "memory");
    __builtin_amdgcn_sched_barrier(0);
    __builtin_amdgcn_s_setprio(1);
#pragma unroll
    for (int mi = 0; mi < 4; ++mi)
#pragma unroll
      for (int nj = 0; nj < 4; ++nj)
        acc[mi + 4][nj] = __builtin_amdgcn_mfma_f32_16x16x32_bf16(
            af1[mi], bfv[nj], acc[mi + 4][nj], 0, 0, 0);
    __builtin_amdgcn_s_setprio(0);
    if (kt + 3 < nk) {
      asm volatile("s_waitcnt vmcnt(8)" ::: "memory");
    } else if (kt + 2 < nk) {
      asm volatile("s_waitcnt vmcnt(4)" ::: "memory");
    } else if (kt + 1 < nk) {
      asm volatile("s_waitcnt vmcnt(0)" ::: "memory");
    }
    __builtin_amdgcn_s_barrier();
  }

#pragma unroll
  for (int mi = 0; mi < 8; ++mi) {
#pragma unroll
    for (int nj = 0; nj < 4; ++nj) {
      f32x4 v = acc[mi][nj];
      int row0 = brow + wm * 128 + mi * 16 + g * 4;
      int colc = bcol + wn * 64 + nj * 16 + c15;
      int which = colc >> 11;           // 0=Q 1=K
      int hc = colc & 2047;
      int bh = ((row0 >> 11) << 4) + (hc >> 7);
      int d = hc & 127, s0 = row0 & 2047;
      unsigned short* dst =
          (which ? Ko : Qo) + ((size_t)bh * 2048 + s0) * 128 + d;
#pragma unroll
      for (int i2 = 0; i2 < 4; ++i2) dst[(size_t)i2 * 128] = f2bf(v[i2]);
    }
  }
}

// ---------------- gemm_v: 128x256x32, 4-deep ring (96KB), grid 32x8=256 ----------------
__global__ __launch_bounds__(512, 2) void gemm_v(
    const unsigned short* __restrict__ A, const unsigned short* __restrict__ B,
    unsigned short* __restrict__ Vt, int Kd) {
  __shared__ unsigned short As[4][64 * 64];    // 4 x 8KB
  __shared__ unsigned short Bs[4][128 * 64];   // 4 x 16KB
  const int t = threadIdx.x;
  const int lane = t & 63, w = t >> 6;
  const int g = lane >> 4, c15 = lane & 15;
  const int wm = w >> 2, wn = w & 3;

  const int chunk = (int)blockIdx.x & 7;
  const int idx = (int)blockIdx.x >> 3;       // 0..31
  const int row = chunk * 4 + (idx >> 3);
  const int col = idx & 7;
  const int brow = row * 128, bcol = col * 256;

  const int l = t >> 3;
  const int lg = (t & 7) ^ (l & 7);
  const unsigned short* srcA = A + (size_t)(brow + l + ((lg >> 2) << 6)) * Kd + (lg & 3) * 8;
  const unsigned short* srcB = B + (size_t)(bcol + l + ((lg >> 2) << 7)) * Kd + (lg & 3) * 8;

  auto stage = [&](int kt) {
    const int buf = kt & 3;
    const unsigned short* a = srcA + kt * 32;
    const unsigned short* b = srcB + kt * 32;
    gld16((char*)As[buf] + t * 16, a);
    gld16((char*)Bs[buf] + t * 16, b);
    gld16((char*)Bs[buf] + 8192 + t * 16, b + (size_t)64 * Kd);
  };

  const int aoff = c15 * 128 + ((((wm << 2) | g) ^ (c15 & 7)) << 4);
  const int boff = ((wn & 1) << 13) + c15 * 128 + (((((wn >> 1) << 2) | g) ^ (c15 & 7)) << 4);

  f32x4 zero4 = {0.f, 0.f, 0.f, 0.f};
  f32x4 acc[4][4];
#pragma unroll
  for (int a_ = 0; a_ < 4; ++a_)
#pragma unroll
    for (int b_ = 0; b_ < 4; ++b_) acc[a_][b_] = zero4;

  const int nk = Kd >> 5;  // 64
  stage(0); stage(1); stage(2);
  asm volatile("s_waitcnt vmcnt(6)" ::: "memory");
  __builtin_amdgcn_s_barrier();

  for (int kt = 0; kt < nk; ++kt) {
    const char* ab = (const char*)As[kt & 3];
    const char* bb = (const char*)Bs[kt & 3];
    bf16x8 bfv[4], af0[2], af1[2];
#pragma unroll
    for (int nj = 0; nj < 4; ++nj) bfv[nj] = *(const bf16x8*)(bb + boff + nj * 2048);
#pragma unroll
    for (int mi = 0; mi < 2; ++mi) af0[mi] = *(const bf16x8*)(ab + aoff + mi * 2048);
    __builtin_amdgcn_sched_barrier(0);
#pragma unroll
    for (int mi = 0; mi < 2; ++mi) af1[mi] = *(const bf16x8*)(ab + aoff + (mi + 2) * 2048);
    if (kt + 3 < nk) stage(kt + 3);
    asm volatile("s_waitcnt lgkmcnt(2)" ::: "memory");
    __builtin_amdgcn_sched_barrier(0);
    __builtin_amdgcn_s_setprio(1);
#pragma unroll
    for (int mi = 0; mi < 2; ++mi)
#pragma unroll
      for (int nj = 0; nj < 4; ++nj)
        acc[mi][nj] = __builtin_amdgcn_mfma_f32_16x16x32_bf16(
            af0[mi], bfv[nj], acc[mi][nj], 0, 0, 0);
    __builtin_amdgcn_s_setprio(0);
    asm volatile("s_waitcnt lgkmcnt(0)" ::: "memory");
    __builtin_amdgcn_sched_barrier(0);
    __builtin_amdgcn_s_setprio(1);
#pragma unroll
    for (int mi = 0; mi < 2; ++mi)
#pragma unroll
      for (int nj = 0; nj < 4; ++nj)
        acc[mi + 2][nj] = __builtin_amdgcn_mfma_f32_16x16x32_bf16(
            af1[mi], bfv[nj], acc[mi + 2][nj], 0, 0, 0);
    __builtin_amdgcn_s_setprio(0);
    if (kt + 3 < nk) {
      asm volatile("s_waitcnt vmcnt(6)" ::: "memory");
    } else if (kt + 3 == nk) {
      asm volatile("s_waitcnt vmcnt(3)" ::: "memory");
    } else if (kt + 2 == nk) {
      asm volatile("s_waitcnt vmcnt(0)" ::: "memory");
    }
    __builtin_amdgcn_s_barrier();
  }

#pragma unroll
  for (int mi = 0; mi < 4; ++mi) {
#pragma unroll
    for (int nj = 0; nj < 4; ++nj) {
      f32x4 v = acc[mi][nj];
      int row0 = brow + wm * 64 + mi * 16 + g * 4;
      int colc = bcol + wn * 64 + nj * 16 + c15;
      int bh = ((row0 >> 11) << 4) + (colc >> 7);
      int d = colc & 127, s0 = row0 & 2047;
      u16x4v pk;
      pk[0] = f2bf(v[0]); pk[1] = f2bf(v[1]); pk[2] = f2bf(v[2]); pk[3] = f2bf(v[3]);
      *(u16x4v*)(Vt + ((size_t)bh * 128 + d) * 2048 + s0) = pk;
    }
  }
}

// ---------------- 128x128x(BK=64) bf16 GEMM (R2-proven) — out-proj ------
__global__ __launch_bounds__(256) void gemm_bt(
    const unsigned short* __restrict__ A, const unsigned short* __restrict__ B,
    float* __restrict__ C, int N, int Kd) {
  __shared__ unsigned short As[128 * 64];
  __shared__ unsigned short Bs[128 * 64];
  const int t = threadIdx.x;
  const int lane = t & 63, w = t >> 6;
  const int g = lane >> 4, c15 = lane & 15;
  const int wr = w >> 1, wc = w & 1;
  const int brow = blockIdx.y * 128, bcol = blockIdx.x * 128;
  const int srow = t >> 3;
  const int ssl = (t & 7) ^ (srow & 7);
  const unsigned short* pA = A + (size_t)(brow + srow) * Kd + ssl * 8;
  const unsigned short* pB = B + (size_t)(bcol + srow) * Kd + ssl * 8;

  int aoff[4][2], boff[4][2];
#pragma unroll
  for (int mi = 0; mi < 4; ++mi)
#pragma unroll
    for (int kk = 0; kk < 2; ++kk) {
      int arow = wr * 64 + mi * 16 + c15;
      int bcolr = wc * 64 + mi * 16 + c15;
      int p = (kk * 4 + g) ^ (c15 & 7);
      aoff[mi][kk] = arow * 128 + (p << 4);
      boff[mi][kk] = bcolr * 128 + (p << 4);
    }
  f32x4 zero4 = {0.f, 0.f, 0.f, 0.f};
  f32x4 acc[4][4];
#pragma unroll
  for (int a_ = 0; a_ < 4; ++a_)
#pragma unroll
    for (int b_ = 0; b_ < 4; ++b_) acc[a_][b_] = zero4;

  const int nk = Kd >> 6;
  for (int kt = 0; kt < nk; ++kt) {
    const unsigned short* a0 = pA + kt * 64;
    const unsigned short* b0 = pB + kt * 64;
#pragma unroll
    for (int c = 0; c < 4; ++c) {
      gld16((char*)As + c * 4096 + t * 16, a0 + (size_t)c * 32 * Kd);
      gld16((char*)Bs + c * 4096 + t * 16, b0 + (size_t)c * 32 * Kd);
    }
    __syncthreads();
    bf16x8 af[4][2], bfv[4][2];
#pragma unroll
    for (int mi = 0; mi < 4; ++mi)
#pragma unroll
      for (int kk = 0; kk < 2; ++kk) {
        af[mi][kk] = *(const bf16x8*)((const char*)As + aoff[mi][kk]);
        bfv[mi][kk] = *(const bf16x8*)((const char*)Bs + boff[mi][kk]);
      }
#pragma unroll
    for (int mi = 0; mi < 4; ++mi)
#pragma unroll
      for (int nj = 0; nj < 4; ++nj)
#pragma unroll
        for (int kk = 0; kk < 2; ++kk)
          acc[mi][nj] = __builtin_amdgcn_mfma_f32_16x16x32_bf16(
              af[mi][kk], bfv[nj][kk], acc[mi][nj], 0, 0, 0);
    __syncthreads();
  }
#pragma unroll
  for (int mi = 0; mi < 4; ++mi)
#pragma unroll
    for (int nj = 0; nj < 4; ++nj) {
      f32x4 v = acc[mi][nj];
      int row0 = brow + wr * 64 + mi * 16 + g * 4;
      int colc = bcol + wc * 64 + nj * 16 + c15;
#pragma unroll
      for (int i = 0; i < 4; ++i) C[(size_t)(row0 + i) * N + colc] = v[i];
    }
}

// ---------------- RoPE (in-place on bf16 Q,K [BH][S][128]); Q gets 1/sqrt(128) folded ----
__global__ __launch_bounds__(256) void rope_apply(
    unsigned short* __restrict__ Q, unsigned short* __restrict__ K,
    const float* __restrict__ ct, const float* __restrict__ st) {
  int id = blockIdx.x * 256 + threadIdx.x;  // 524288 = 32*2048*8
  int o = id & 7;
  int s = (id >> 3) & 2047;
  int bh = id >> 14;
  size_t base = ((size_t)bh * 2048 + s) * 128 + o * 8;
  u16x8v qlo = *(u16x8v*)(Q + base), qhi = *(u16x8v*)(Q + base + 64);
  u16x8v klo = *(u16x8v*)(K + base), khi = *(u16x8v*)(K + base + 64);
  const float* cp = ct + s * 64 + o * 8;
  const float* sp = st + s * 64 + o * 8;
#pragma unroll
  for (int j = 0; j < 8; ++j) {
    float c = cp[j], sn = sp[j];
    float ql = bf2f(qlo[j]), qh = bf2f(qhi[j]);
    qlo[j] = f2bf((ql * c - qh * sn) * SCALE_Q);
    qhi[j] = f2bf((qh * c + ql * sn) * SCALE_Q);
    float kl = bf2f(klo[j]), kh = bf2f(khi[j]);
    klo[j] = f2bf(kl * c - kh * sn);
    khi[j] = f2bf(kh * c + kl * sn);
  }
  *(u16x8v*)(Q + base) = qlo; *(u16x8v*)(Q + base + 64) = qhi;
  *(u16x8v*)(K + base) = klo; *(u16x8v*)(K + base + 64) = khi;
}

// ---------------- attn_fwd R11: QBLK=128 (8 waves x 16 rows), KVB=64, grid 8x32 ----------
// Paired q-blocks p & 15-p -> uniform 34 tiles/block; 256 blocks = 1/CU (LDS 88KB).
// Counted-vmcnt dbuf: per tile {stage(next) 4 gld16; vmcnt(4); barrier; compute; barrier}.
// Overwrite safety: stage(t+1) targets buffer read at t-1, closed by t-1's end barrier.
// Defer-max (T13): skip O/l rescale when all rows' max growth <= 8 (P bounded by e^8).
__global__ __launch_bounds__(512) void attn_fwd(
    const unsigned short* __restrict__ Qg, const unsigned short* __restrict__ Kg,
    const unsigned short* __restrict__ Vtg, unsigned short* __restrict__ Og) {
  __shared__ unsigned short Ks[2][64 * 128];   // [kv64][d128] 256B rows, swz ^(row&15)
  __shared__ unsigned short Vs[2][128 * 64];   // [d128][kv64] 128B rows, swz ^(row&7)
  __shared__ unsigned short Pl[8][16 * 88];    // per-wave P buffer
  const int t = threadIdx.x;
  const int lane = t & 63, w = t >> 6;         // w 0..7
  const int g = lane >> 4, c15 = lane & 15;
  const int pair = blockIdx.x;                 // 0..7
  const int bh = blockIdx.y;
  const int b = bh >> 4, h = bh & 15;

  const int ksrow = t >> 4;                    // 0..31
  const int kssl = (t & 15) ^ (ksrow & 15);
  const unsigned short* kp = Kg + ((size_t)bh * 2048 + ksrow) * 128 + kssl * 8;
  const int vsrow = t >> 3;                    // 0..63
  const int vssl = (t & 7) ^ (vsrow & 7);
  const unsigned short* vp = Vtg + ((size_t)bh * 128 + vsrow) * 2048 + vssl * 8;

  auto stageTile = [&](int buf, int tkv) {     // 4 gld16/thread = 32KB total
    gld16((char*)Ks[buf] + t * 16, kp + (size_t)(tkv * 64) * 128);
    gld16((char*)Ks[buf] + 8192 + t * 16, kp + (size_t)(tkv * 64 + 32) * 128);
    gld16((char*)Vs[buf] + t * 16, vp + tkv * 64);
    gld16((char*)Vs[buf] + 8192 + t * 16, vp + (size_t)64 * 2048 + tkv * 64);
  };

  f32x4 zero4 = {0.f, 0.f, 0.f, 0.f};
  f32x4 o[8];
  float mrow[4], lrow[4];
  bf16x8 qf[4];

  auto loadQ = [&](int qb) {
    const unsigned short* qp =
        Qg + ((size_t)bh * 2048 + qb * 128 + w * 16 + c15) * 128 + g * 8;
#pragma unroll
    for (int kf = 0; kf < 4; ++kf) qf[kf] = *(const bf16x8*)(qp + kf * 32);
#pragma unroll
    for (int db = 0; db < 8; ++db) o[db] = zero4;
#pragma unroll
    for (int i = 0; i < 4; ++i) { mrow[i] = -1e30f; lrow[i] = 0.f; }
  };

  auto computeTile = [&](int buf, int qb, int tkv) {
    const int qrow = qb * 128 + w * 16;
    f32x4 sv[4];
    __builtin_amdgcn_s_setprio(1);
#pragma unroll
    for (int cb = 0; cb < 4; ++cb) {
      f32x4 z = zero4;
#pragma unroll
      for (int kf = 0; kf < 4; ++kf) {
        int rowk = cb * 16 + c15;
        int p = (kf * 4 + g) ^ c15;
        bf16x8 kfr = *(const bf16x8*)((const char*)Ks[buf] + rowk * 256 + p * 16);
        z = __builtin_amdgcn_mfma_f32_16x16x32_bf16(qf[kf], kfr, z, 0, 0, 0);
      }
      sv[cb] = z;
    }
    __builtin_amdgcn_s_setprio(0);
    if (tkv >= 2 * qb) {  // diagonal tiles causal mask
#pragma unroll
      for (int cb = 0; cb < 4; ++cb)
#pragma unroll
        for (int i = 0; i < 4; ++i) {
          int colk = tkv * 64 + cb * 16 + c15;
          int rq = qrow + g * 4 + i;
          if (colk > rq) sv[cb][i] = -1e30f;
        }
    }
    // row max (16-lane groups hold a row's 64 kv cols)
    float pmx[4];
#pragma unroll
    for (int i = 0; i < 4; ++i)
      pmx[i] = fmaxf(fmaxf(sv[0][i], sv[1][i]), fmaxf(sv[2][i], sv[3][i]));
#pragma unroll
    for (int dd = 1; dd < 16; dd <<= 1)
#pragma unroll
      for (int i = 0; i < 4; ++i) pmx[i] = fmaxf(pmx[i], __shfl_xor(pmx[i], dd));
    // defer-max (T13): rescale only if some row grew > 8
    int grow = 0;
#pragma unroll
    for (int i = 0; i < 4; ++i) grow |= (pmx[i] > mrow[i] + 8.0f) ? 1 : 0;
    if (__any(grow)) {
#pragma unroll
      for (int i = 0; i < 4; ++i) {
        float nm = fmaxf(mrow[i], pmx[i]);
        float sc = __expf(mrow[i] - nm);
        mrow[i] = nm;
        lrow[i] *= sc;
#pragma unroll
        for (int db = 0; db < 8; ++db) o[db][i] *= sc;
      }
    }
    float psum[4] = {0.f, 0.f, 0.f, 0.f};
#pragma unroll
    for (int cb = 0; cb < 4; ++cb)
#pragma unroll
      for (int i = 0; i < 4; ++i) {
        float e = __expf(sv[cb][i] - mrow[i]);
        sv[cb][i] = e;
        psum[i] += e;
      }
#pragma unroll
    for (int dd = 1; dd < 16; dd <<= 1)
#pragma unroll
      for (int i = 0; i < 4; ++i) psum[i] += __shfl_xor(psum[i], dd);
#pragma unroll
    for (int i = 0; i < 4; ++i) lrow[i] += psum[i];

    // P: C-layout -> A-layout via per-wave LDS
    unsigned short* pw = &Pl[w][0];
#pragma unroll
    for (int cb = 0; cb < 4; ++cb)
#pragma unroll
      for (int i = 0; i < 4; ++i)
        pw[(g * 4 + i) * 88 + cb * 16 + c15] = f2bf(sv[cb][i]);
    bf16x8 pf[2];
#pragma unroll
    for (int kb = 0; kb < 2; ++kb)
      pf[kb] = *(const bf16x8*)((const char*)pw + c15 * 176 + kb * 64 + g * 16);

    __builtin_amdgcn_s_setprio(1);
#pragma unroll
    for (int db = 0; db < 8; ++db) {
#pragma unroll
      for (int kb = 0; kb < 2; ++kb) {
        int rowv = db * 16 + c15;
        int p = (kb * 4 + g) ^ (c15 & 7);
        bf16x8 vfr = *(const bf16x8*)((const char*)Vs[buf] + rowv * 128 + p * 16);
        o[db] = __builtin_amdgcn_mfma_f32_16x16x32_bf16(pf[kb], vfr, o[db], 0, 0, 0);
      }
    }
    __builtin_amdgcn_s_setprio(0);
  };

  auto writeO = [&](int qb) {
    float linv[4];
#pragma unroll
    for (int i = 0; i < 4; ++i) linv[i] = 1.0f / lrow[i];
#pragma unroll
    for (int db = 0; db < 8; ++db)
#pragma unroll
      for (int i = 0; i < 4; ++i) {
        int q = qb * 128 + w * 16 + g * 4 + i;
        Og[((size_t)(b * 2048 + q)) * 2048 + h * 128 + db * 16 + c15] =
            f2bf(o[db][i] * linv[i]);
      }
  };

  const int qbA = pair, qbB = 15 - pair;       // q-blocks of 128 rows
  const int ntA = 2 * qbA + 2, ntB = 2 * qbB + 2;  // 34 tiles total, uniform
  int cur = 0;

  stageTile(0, 0);
  loadQ(qbA);
  for (int tkv = 0; tkv < ntA; ++tkv) {
    if (tkv + 1 < ntA) stageTile(cur ^ 1, tkv + 1);
    else               stageTile(cur ^ 1, 0);          // first tile of half B
    asm volatile("s_waitcnt vmcnt(4)" ::: "memory");   // current buf landed
    __builtin_amdgcn_s_barrier();
    computeTile(cur, qbA, tkv);
    __builtin_amdgcn_s_barrier();                      // close reads of buf[cur]
    cur ^= 1;
  }
  writeO(qbA);
  loadQ(qbB);
  for (int tkv = 0; tkv < ntB; ++tkv) {
    if (tkv + 1 < ntB) {
      stageTile(cur ^ 1, tkv + 1);
      asm volatile("s_waitcnt vmcnt(4)" ::: "memory");
    } else {
      asm volatile("s_waitcnt vmcnt(0)" ::: "memory");
    }
    __builtin_amdgcn_s_barrier();
    computeTile(cur, qbB, tkv);
    __builtin_amdgcn_s_barrier();
    cur ^= 1;
  }
  writeO(qbB);
}

extern "C" void kernel_launch(void* const* d_in, const int* in_sizes, int n_in,
                              void* d_out, int out_size, void* d_ws, size_t ws_size,
                              hipStream_t stream) {
  const float* x  = (const float*)d_in[0];
  const float* Wq = (const float*)d_in[1];
  const float* Wk = (const float*)d_in[2];
  const float* Wv = (const float*)d_in[3];
  const float* Wo = (const float*)d_in[4];
  char* p = (char*)d_ws;
  unsigned short* xb    = (unsigned short*)p;                 // 16 MB (reused as Ao)
  unsigned short* wqkvb = (unsigned short*)(p + 16777216);    // 24 MB
  unsigned short* wob   = (unsigned short*)(p + 41943040);    //  8 MB
  unsigned short* Qb    = (unsigned short*)(p + 50331648);    // 16 MB
  unsigned short* Kb    = (unsigned short*)(p + 67108864);    // 16 MB
  unsigned short* Vt    = (unsigned short*)(p + 83886080);    // 16 MB
  float* ctab           = (float*)(p + 100663296);            // 0.5 MB
  float* stab           = (float*)(p + 101187584);            // 0.5 MB -> end 101711872
  unsigned short* Ao = xb;  // xb dead after QKV gemms

  cvt_all<<<dim3(4096, 5), 256, 0, stream>>>(x, Wq, Wk, Wv, Wo, xb, wqkvb, wob);
  rope_table<<<512, 256, 0, stream>>>(ctab, stab);
  gemm_qk<<<256, 512, 0, stream>>>(xb, wqkvb, Qb, Kb, 2048);
  gemm_v<<<256, 512, 0, stream>>>(xb, wqkvb + (size_t)4096 * 2048, Vt, 2048);
  rope_apply<<<2048, 256, 0, stream>>>(Qb, Kb, ctab, stab);
  attn_fwd<<<dim3(8, 32), 512, 0, stream>>>(Qb, Kb, Vt, Ao);
  gemm_bt<<<dim3(16, 32), 256, 0, stream>>>(Ao, wob, (float*)d_out, 2048, 2048);
}